// Round 7
// baseline (288.724 us; speedup 1.0000x reference)
//
#include <hip/hip_runtime.h>
#include <hip/hip_bf16.h>

typedef unsigned short u16;
typedef __attribute__((ext_vector_type(8))) short short8;
typedef __attribute__((ext_vector_type(4))) short short4v;
typedef __attribute__((ext_vector_type(8))) u16 u16x8;
typedef __attribute__((ext_vector_type(4))) u16 u16x4;
typedef __attribute__((ext_vector_type(4))) float f32x4;

__device__ __forceinline__ u16 f2bf(float f) {
  __hip_bfloat16 h = __float2bfloat16(f);
  u16 u;
  __builtin_memcpy(&u, &h, 2);
  return u;
}

__device__ __forceinline__ f32x4 mfma16(short8 a, short8 b, f32x4 c) {
  return __builtin_amdgcn_mfma_f32_16x16x32_bf16(a, b, c, 0, 0, 0);
}

__device__ __forceinline__ f32x4 mfma16x16(short4v a, short4v b, f32x4 c) {
#if __has_builtin(__builtin_amdgcn_mfma_f32_16x16x16bf16_1k)
  return __builtin_amdgcn_mfma_f32_16x16x16bf16_1k(a, b, c, 0, 0, 0);
#else
  asm("v_mfma_f32_16x16x16_bf16 %0, %1, %2, %0" : "+v"(c) : "v"(a), "v"(b));
  return c;
#endif
}

__device__ __forceinline__ void gl_lds16(const void* g, void* l) {
  __builtin_amdgcn_global_load_lds(
      (const __attribute__((address_space(1))) unsigned int*)g,
      (__attribute__((address_space(3))) unsigned int*)l, 16, 0, 0);
}

// ---------------- convert x fp32 -> bf16 ----------------
__global__ __launch_bounds__(256) void cvt_x_k(const float* __restrict__ x,
                                               u16* __restrict__ xb) {
  int i = (blockIdx.x * 256 + threadIdx.x) * 4;
  float4 v = *(const float4*)(x + i);
  u16x4 o = { f2bf(v.x), f2bf(v.y), f2bf(v.z), f2bf(v.w) };
  *(u16x4*)(xb + i) = o;
}

// ---------------- transpose + convert weight: wt[n][k] = w[k][n], K=768 ----
__global__ __launch_bounds__(256) void cvt_wt_k(const float* __restrict__ w,
                                                u16* __restrict__ wt, int N) {
  int i = blockIdx.x * 256 + threadIdx.x;  // over N*768
  int nn = i / 768, kk = i % 768;
  wt[i] = f2bf(w[(size_t)kk * N + nn]);
}

// ---------------- CPB bias MLP: 729 entries x (2->512->24), 16*sigmoid -----
__device__ __forceinline__ float cpb_coord(int v) {
  float c = (float)(v - 13) * (8.0f / 13.0f);
  float a = fabsf(c);
  float r = log2f(a + 1.0f) * (1.0f / 3.0f);
  return c < 0.f ? -r : r;
}

__global__ __launch_bounds__(64) void bias_mlp_k(
    const float* __restrict__ w1, const float* __restrict__ b1,
    const float* __restrict__ w2, const float* __restrict__ b2,
    float* __restrict__ btab) {
  int e = blockIdx.x;
  int lane = threadIdx.x;
  float t0 = cpb_coord(e / 27), t1 = cpb_coord(e % 27);
  float acc[24];
#pragma unroll
  for (int hh = 0; hh < 24; hh++) acc[hh] = 0.f;
#pragma unroll
  for (int jj = 0; jj < 8; jj++) {
    int j = lane * 8 + jj;
    float h1 = t0 * w1[j] + t1 * w1[512 + j] + b1[j];
    h1 = fmaxf(h1, 0.f);
#pragma unroll
    for (int hh = 0; hh < 24; hh++) acc[hh] += h1 * w2[j * 24 + hh];
  }
#pragma unroll
  for (int hh = 0; hh < 24; hh++)
#pragma unroll
    for (int m = 1; m < 64; m <<= 1) acc[hh] += __shfl_xor(acc[hh], m, 64);
  if (lane == 0) {
#pragma unroll
    for (int hh = 0; hh < 24; hh++) {
      float v = acc[hh] + b2[hh];
      btab[e * 24 + hh] = 16.f / (1.f + __expf(-v));
    }
  }
}

// ---------------- expand bias to [24][196][208] fp32, pre-scaled by log2e --
__global__ __launch_bounds__(256) void bias_expand_k(const float* __restrict__ tab,
                                                     float* __restrict__ be) {
  int i = blockIdx.x * 256 + threadIdx.x;  // 24*196*208
  int h = i / (196 * 208);
  int rem = i % (196 * 208);
  int row = rem / 208, col = rem % 208;
  float v = 0.f;
  if (col < 196) {
    int dy = row / 14 - col / 14 + 13;
    int dx = row % 14 - col % 14 + 13;
    v = tab[(dy * 27 + dx) * 24 + h] * 1.4426950408889634f;
  }
  be[i] = v;
}

// ---------------- GEMM: C = A[M][K] * Bt[N][K]^T + bias -------------------
// Natural row-major output. EPI=0: bf16 to Cb. EPI=1: fp32 to Cf.
// BK=64, chunk-XOR LDS swizzle, XCD-chunked block swizzle (nwg % 8 == 0).
template <int EPI>
__global__ __launch_bounds__(256) void gemm_k(
    const u16* __restrict__ A, const u16* __restrict__ Bt,
    const float* __restrict__ bias, float* __restrict__ Cf,
    u16* __restrict__ Cb, int N, int K, int nbx) {
  __shared__ u16 As[128 * 64];
  __shared__ u16 Bs[128 * 64];
  const int tid = threadIdx.x, lane = tid & 63, w = tid >> 6;
  const int r16 = lane & 15, q4 = lane >> 4;
  const int wr = w >> 1, wc = w & 1;
  // XCD-chunked bijective swizzle: same-m blocks grouped per XCD
  const int nwg = gridDim.x, cpx = nwg >> 3;
  const int swz = (blockIdx.x & 7) * cpx + (blockIdx.x >> 3);
  const int m0 = (swz / nbx) * 128, n0 = (swz % nbx) * 128;

  f32x4 acc[4][4] = {};

  for (int k0 = 0; k0 < K; k0 += 64) {
#pragma unroll
    for (int g = 0; g < 4; g++) {
      int chunk = (w * 4 + g) * 64 + lane;
      int row = chunk >> 3, p = chunk & 7;
      int gch = p ^ (row & 7);
      gl_lds16(A + (size_t)(m0 + row) * K + k0 + gch * 8, (char*)As + (w * 4 + g) * 1024);
      gl_lds16(Bt + (size_t)(n0 + row) * K + k0 + gch * 8, (char*)Bs + (w * 4 + g) * 1024);
    }
    __syncthreads();
#pragma unroll
    for (int kk = 0; kk < 2; kk++) {
      short8 af[4], bfr[4];
#pragma unroll
      for (int i = 0; i < 4; i++) {
        int row = wr * 64 + i * 16 + r16;
        int pc = (kk * 4 + q4) ^ (r16 & 7);
        af[i] = *(const short8*)((const char*)As + row * 128 + pc * 16);
      }
#pragma unroll
      for (int j = 0; j < 4; j++) {
        int row = wc * 64 + j * 16 + r16;
        int pc = (kk * 4 + q4) ^ (r16 & 7);
        bfr[j] = *(const short8*)((const char*)Bs + row * 128 + pc * 16);
      }
#pragma unroll
      for (int i = 0; i < 4; i++)
#pragma unroll
        for (int j = 0; j < 4; j++) acc[i][j] = mfma16(af[i], bfr[j], acc[i][j]);
    }
    __syncthreads();
  }

  // epilogue: natural row-major writes, no div/mod
  const int nb = n0 + wc * 64 + r16;
  float bn[4];
#pragma unroll
  for (int j = 0; j < 4; j++) bn[j] = bias[nb + j * 16];
#pragma unroll
  for (int i = 0; i < 4; i++) {
#pragma unroll
    for (int r = 0; r < 4; r++) {
      int m = m0 + wr * 64 + i * 16 + q4 * 4 + r;
      if (EPI == 1) {
        float* cp = Cf + (size_t)m * N + nb;
#pragma unroll
        for (int j = 0; j < 4; j++) cp[j * 16] = acc[i][j][r] + bn[j];
      } else {
        u16* cp = Cb + (size_t)m * N + nb;
#pragma unroll
        for (int j = 0; j < 4; j++) cp[j * 16] = f2bf(acc[i][j][r] + bn[j]);
      }
    }
  }
}

// ---------------- attention: one block per (b,h) --------------------------
// Swapped QK^T (S^T = mfma(K,Q)) -> P lane-local -> PV via 16x16x16 MFMA.
// No-max softmax; 1/sum deferred to output with row-transposing shuffle.
// R7: QK->exp2->bf16 FUSED per tile so p[t] dies immediately (peak live
// ~26 pa regs instead of 52 p + 52 bv) -> target VGPR <=128 for 4+ waves/
// SIMD (R6 was 140 VGPR = 3 waves/SIMD, latency-bound at VALUBusy 24%).
// setprio(1) around PV MFMA cluster (T5: attn-proven, independent blocks).
__global__ __launch_bounds__(256) void attn_k(
    const u16* __restrict__ qkv, const float* __restrict__ be,
    u16* __restrict__ ao) {
  constexpr int VST = 236;
  __shared__ u16 Ks[208 * 32];   // swizzled 16B chunks, rows 0..207
  __shared__ u16 Vt[32 * VST];   // V transposed: Vt[d][n]
  const int tid = threadIdx.x, lane = tid & 63, w = tid >> 6;
  const int r16 = lane & 15, q4 = lane >> 4;
  const int bh = blockIdx.x, b = bh / 24, h = bh % 24;
  const u16* qp = qkv + (size_t)(b * 196) * 2304 + h * 32;
  const u16* kp = qp + 768;
  const u16* vp = qp + 1536;
  const float* bp = be + h * (196 * 208);
  const int ksw = (q4 ^ ((r16 >> 1) & 3)) * 16;
  const float SC2 = 0.17677669529663687f * 1.4426950408889634f;  // 1/sqrt(32)*log2e

  // stage K rows 0..207 (rows >=196 are garbage; masked before use)
  for (int g = w; g < 13; g += 4) {
    int chunk = g * 64 + lane;
    int row = chunk >> 2;
    int gch = (chunk & 3) ^ ((row >> 1) & 3);
    gl_lds16(kp + (size_t)row * 2304 + gch * 8, (char*)Ks + g * 1024);
  }
  // stage V transposed (rows 0..195 only)
  for (int c = tid; c < 784; c += 256) {
    int n = c >> 2, d0 = (c & 3) * 8;
    u16x8 vv = *(const u16x8*)(vp + (size_t)n * 2304 + (c & 3) * 8);
#pragma unroll
    for (int jj = 0; jj < 8; jj++) Vt[(d0 + jj) * VST + n] = vv[jj];
  }
  // zero Vt pad cols 196..235
  for (int idx = tid; idx < 32 * 40; idx += 256) {
    int d = idx / 40, n = 196 + idx % 40;
    Vt[d * VST + n] = 0;
  }
  __syncthreads();

  const f32x4 z = {0.f, 0.f, 0.f, 0.f};
  // prefetched Q fragment for the first strip
  short8 bq = *(const short8*)(qp + (size_t)(w * 16 + r16) * 2304 + q4 * 8);
  for (int si = w; si < 13; si += 4) {
    // prefetch next strip's Q (hides global latency under softmax+PV)
    short8 bq_next = {};
    if (si + 4 < 13)
      bq_next = *(const short8*)(qp + (size_t)((si + 4) * 16 + r16) * 2304 + q4 * 8);
    int gc = si * 16 + r16;
    gc = gc < 196 ? gc : 195;
    const float* brow = bp + gc * 208 + q4 * 4;
    // fused QK -> scale+bias -> exp2 -> bf16 (unnormalized), per tile:
    // p dies into 2-reg pa[t] immediately; 4 parallel sum chains.
    float s0 = 0.f, s1 = 0.f, s2 = 0.f, s3 = 0.f;
    short4v pa[13];
#pragma unroll
    for (int t = 0; t < 13; t++) {
      short8 ka = *(const short8*)((const char*)Ks + (t * 16 + r16) * 64 + ksw);
      f32x4 p = mfma16(ka, bq, z);
      float4 bv = *(const float4*)(brow + t * 16);
      float e0 = __builtin_amdgcn_exp2f(p[0] * SC2 + bv.x);
      float e1 = __builtin_amdgcn_exp2f(p[1] * SC2 + bv.y);
      float e2 = __builtin_amdgcn_exp2f(p[2] * SC2 + bv.z);
      float e3 = __builtin_amdgcn_exp2f(p[3] * SC2 + bv.w);
      if (t == 12) {  // keys 192..207: mask k >= 196 (also kills NaN from OOB K)
        int k0 = 192 + q4 * 4;
        e0 = (k0 + 0 < 196) ? e0 : 0.f;
        e1 = (k0 + 1 < 196) ? e1 : 0.f;
        e2 = (k0 + 2 < 196) ? e2 : 0.f;
        e3 = (k0 + 3 < 196) ? e3 : 0.f;
      }
      s0 += e0; s1 += e1; s2 += e2; s3 += e3;
      pa[t][0] = (short)f2bf(e0);
      pa[t][1] = (short)f2bf(e1);
      pa[t][2] = (short)f2bf(e2);
      pa[t][3] = (short)f2bf(e3);
    }
    bq = bq_next;
    float sum = (s0 + s1) + (s2 + s3);
    sum += __shfl_xor(sum, 16, 64);
    sum += __shfl_xor(sum, 32, 64);   // every lane: total for q-row r16
    float rs = 1.0f / sum;
    // PV with unnormalized P; 4 short accumulator chains
    f32x4 o0a = z, o0b = z, o1a = z, o1b = z;
    __builtin_amdgcn_s_setprio(1);
#pragma unroll
    for (int t = 0; t < 13; t++) {
      const u16* vrow = &Vt[r16 * VST + t * 16 + q4 * 4];
      short4v b0 = *(const short4v*)vrow;
      short4v b1 = *(const short4v*)(vrow + 16 * VST);
      if (t & 1) {
        o0b = mfma16x16(pa[t], b0, o0b);
        o1b = mfma16x16(pa[t], b1, o1b);
      } else {
        o0a = mfma16x16(pa[t], b0, o0a);
        o1a = mfma16x16(pa[t], b1, o1a);
      }
    }
    __builtin_amdgcn_s_setprio(0);
    // write O (bf16): lane (r16,q4) reg r -> q-row q4*4+r, col d=r16 (+16).
    // Normalizer of q-row q4*4+r comes from lane (lane&~15)|(q4*4+r).
#pragma unroll
    for (int r = 0; r < 4; r++) {
      float rsv = __shfl(rs, q4 * 4 + r, 16);
      int grow = si * 16 + q4 * 4 + r;
      if (grow < 196) {
        u16* op = ao + ((size_t)(b * 196 + grow)) * 768 + h * 32;
        op[r16] = f2bf((o0a[r] + o0b[r]) * rsv);
        op[16 + r16] = f2bf((o1a[r] + o1b[r]) * rsv);
      }
    }
  }
}

// ---------------------------------------------------------------------------
extern "C" void kernel_launch(void* const* d_in, const int* in_sizes, int n_in,
                              void* d_out, int out_size, void* d_ws, size_t ws_size,
                              hipStream_t stream) {
  const float* x = (const float*)d_in[0];
  const float* qkv_w = (const float*)d_in[1];
  const float* qkv_b = (const float*)d_in[2];
  const float* proj_w = (const float*)d_in[3];
  const float* proj_b = (const float*)d_in[4];
  const float* cpb_w1 = (const float*)d_in[5];
  const float* cpb_b1 = (const float*)d_in[6];
  const float* cpb_w2 = (const float*)d_in[7];
  const float* cpb_b2 = (const float*)d_in[8];
  float* out = (float*)d_out;

  char* ws = (char*)d_ws;
  size_t o = 0;
  auto alloc = [&](size_t sz) {
    size_t r = o;
    o = (o + sz + 255) & ~(size_t)255;
    return r;
  };
  const size_t ME = (size_t)25088 * 768;  // elems per [B,N,DIM]-sized tensor
  u16* x_bf = (u16*)(ws + alloc(ME * 2));           // also aliased as attnout
  u16* wq_t = (u16*)(ws + alloc((size_t)2304 * 768 * 2));
  u16* wp_t = (u16*)(ws + alloc((size_t)768 * 768 * 2));
  u16* qkv_s = (u16*)(ws + alloc(3 * ME * 2));      // [25088][2304] bf16
  float* btab = (float*)(ws + alloc((size_t)729 * 24 * 4));   // also OOB-read pad
  float* bexp = (float*)(ws + alloc((size_t)24 * 196 * 208 * 4));
  u16* ao = x_bf;  // alias: x_bf dead after qkv GEMM

  cvt_x_k<<<18816, 256, 0, stream>>>(x, x_bf);
  cvt_wt_k<<<6912, 256, 0, stream>>>(qkv_w, wq_t, 2304);
  cvt_wt_k<<<2304, 256, 0, stream>>>(proj_w, wp_t, 768);
  bias_mlp_k<<<729, 64, 0, stream>>>(cpb_w1, cpb_b1, cpb_w2, cpb_b2, btab);
  bias_expand_k<<<3822, 256, 0, stream>>>(btab, bexp);
  gemm_k<0><<<3528, 256, 0, stream>>>(x_bf, wq_t, qkv_b, nullptr, qkv_s,
                                      2304, 768, 18);
  attn_k<<<3072, 256, 0, stream>>>(qkv_s, bexp, ao);
  gemm_k<1><<<1176, 256, 0, stream>>>(ao, wp_t, proj_b, out, nullptr,
                                      768, 768, 6);
}

// Round 8
// 283.924 us; speedup vs baseline: 1.0169x; 1.0169x over previous
//
#include <hip/hip_runtime.h>
#include <hip/hip_bf16.h>

typedef unsigned short u16;
typedef __attribute__((ext_vector_type(8))) short short8;
typedef __attribute__((ext_vector_type(4))) short short4v;
typedef __attribute__((ext_vector_type(8))) u16 u16x8;
typedef __attribute__((ext_vector_type(4))) u16 u16x4;
typedef __attribute__((ext_vector_type(4))) float f32x4;

__device__ __forceinline__ u16 f2bf(float f) {
  __hip_bfloat16 h = __float2bfloat16(f);
  u16 u;
  __builtin_memcpy(&u, &h, 2);
  return u;
}

__device__ __forceinline__ f32x4 mfma16(short8 a, short8 b, f32x4 c) {
  return __builtin_amdgcn_mfma_f32_16x16x32_bf16(a, b, c, 0, 0, 0);
}

__device__ __forceinline__ f32x4 mfma16x16(short4v a, short4v b, f32x4 c) {
#if __has_builtin(__builtin_amdgcn_mfma_f32_16x16x16bf16_1k)
  return __builtin_amdgcn_mfma_f32_16x16x16bf16_1k(a, b, c, 0, 0, 0);
#else
  asm("v_mfma_f32_16x16x16_bf16 %0, %1, %2, %0" : "+v"(c) : "v"(a), "v"(b));
  return c;
#endif
}

__device__ __forceinline__ void gl_lds16(const void* g, void* l) {
  __builtin_amdgcn_global_load_lds(
      (const __attribute__((address_space(1))) unsigned int*)g,
      (__attribute__((address_space(3))) unsigned int*)l, 16, 0, 0);
}

// ---------------- convert x fp32 -> bf16 ----------------
__global__ __launch_bounds__(256) void cvt_x_k(const float* __restrict__ x,
                                               u16* __restrict__ xb) {
  int i = (blockIdx.x * 256 + threadIdx.x) * 4;
  float4 v = *(const float4*)(x + i);
  u16x4 o = { f2bf(v.x), f2bf(v.y), f2bf(v.z), f2bf(v.w) };
  *(u16x4*)(xb + i) = o;
}

// ---------------- transpose + convert weight: wt[n][k] = w[k][n], K=768 ----
__global__ __launch_bounds__(256) void cvt_wt_k(const float* __restrict__ w,
                                                u16* __restrict__ wt, int N) {
  int i = blockIdx.x * 256 + threadIdx.x;  // over N*768
  int nn = i / 768, kk = i % 768;
  wt[i] = f2bf(w[(size_t)kk * N + nn]);
}

// ---------------- CPB bias MLP: 729 entries x (2->512->24), 16*sigmoid -----
__device__ __forceinline__ float cpb_coord(int v) {
  float c = (float)(v - 13) * (8.0f / 13.0f);
  float a = fabsf(c);
  float r = log2f(a + 1.0f) * (1.0f / 3.0f);
  return c < 0.f ? -r : r;
}

__global__ __launch_bounds__(64) void bias_mlp_k(
    const float* __restrict__ w1, const float* __restrict__ b1,
    const float* __restrict__ w2, const float* __restrict__ b2,
    float* __restrict__ btab) {
  int e = blockIdx.x;
  int lane = threadIdx.x;
  float t0 = cpb_coord(e / 27), t1 = cpb_coord(e % 27);
  float acc[24];
#pragma unroll
  for (int hh = 0; hh < 24; hh++) acc[hh] = 0.f;
#pragma unroll
  for (int jj = 0; jj < 8; jj++) {
    int j = lane * 8 + jj;
    float h1 = t0 * w1[j] + t1 * w1[512 + j] + b1[j];
    h1 = fmaxf(h1, 0.f);
#pragma unroll
    for (int hh = 0; hh < 24; hh++) acc[hh] += h1 * w2[j * 24 + hh];
  }
#pragma unroll
  for (int hh = 0; hh < 24; hh++)
#pragma unroll
    for (int m = 1; m < 64; m <<= 1) acc[hh] += __shfl_xor(acc[hh], m, 64);
  if (lane == 0) {
#pragma unroll
    for (int hh = 0; hh < 24; hh++) {
      float v = acc[hh] + b2[hh];
      btab[e * 24 + hh] = 16.f / (1.f + __expf(-v));
    }
  }
}

// ---------------- expand bias to [24][196][208] fp32, pre-scaled by log2e --
__global__ __launch_bounds__(256) void bias_expand_k(const float* __restrict__ tab,
                                                     float* __restrict__ be) {
  int i = blockIdx.x * 256 + threadIdx.x;  // 24*196*208
  int h = i / (196 * 208);
  int rem = i % (196 * 208);
  int row = rem / 208, col = rem % 208;
  float v = 0.f;
  if (col < 196) {
    int dy = row / 14 - col / 14 + 13;
    int dx = row % 14 - col % 14 + 13;
    v = tab[(dy * 27 + dx) * 24 + h] * 1.4426950408889634f;
  }
  be[i] = v;
}

// ---------------- 256x256 8-wave 4-phase pipelined GEMM (K=768) ------------
// C[m][n] bf16 = A[M][768] * Bt[N][768]^T + bias. dbuf per K-step (BK=64),
// counted vmcnt(2) once per K-step (T3+T4), setprio around MFMA (T5),
// chunk-XOR LDS swizzle (0-conflict, same scheme as gemm_k), bijective XCD
// block swizzle (nwg%8 != 0 safe).
__global__ __launch_bounds__(512) void gemm256_k(
    const u16* __restrict__ A, const u16* __restrict__ Bt,
    const float* __restrict__ bias, u16* __restrict__ Cb, int N, int nbx) {
  __shared__ u16 lds[65536];  // 128 KiB: A buffers at 0/32768 B, B at 65536+
  char* ldsb = (char*)lds;
  const int tid = threadIdx.x, lane = tid & 63, w = tid >> 6;
  const int r16 = lane & 15, q4 = lane >> 4;
  const int wm = w >> 2, wn = w & 3;
  // bijective XCD-chunked swizzle (m204 form)
  const int nwg = gridDim.x;
  const int qq = nwg >> 3, rr = nwg & 7;
  const int xcd = blockIdx.x & 7, bidx = blockIdx.x >> 3;
  const int swz = (xcd < rr) ? xcd * (qq + 1) + bidx
                             : rr * (qq + 1) + (xcd - rr) * qq + bidx;
  const int m0 = (swz / nbx) * 256, n0 = (swz % nbx) * 256;
  const u16* Ab = A + (size_t)m0 * 768;
  const u16* Bb = Bt + (size_t)n0 * 768;

  // stage one half-tile (128 rows x 64 cols) of K-step sdst into buf sdst&1.
  // matBase: 0 for A, 65536 for B (bytes). 2 gl_lds per thread.
  auto stage = [&](const u16* __restrict__ src, int matBase, int sdst, int h) {
    char* base = ldsb + matBase + (sdst & 1) * 32768 + h * 16384 + w * 1024;
    const int k0 = sdst * 64;
#pragma unroll
    for (int g = 0; g < 2; g++) {
      int c = g * 512 + tid;
      int row = c >> 3, p = c & 7;
      int gch = p ^ (row & 7);
      gl_lds16(src + (size_t)(h * 128 + row) * 768 + k0 + gch * 8,
               base + g * 8192 + lane * 16);
    }
  };

  f32x4 acc[8][4] = {};

  // prologue: all 4 half-tiles of K-step 0 + A-h0 of K-step 1 (10 loads);
  // vmcnt(2) allows only A-h0(1) in flight -> K-step 0 fully landed.
  stage(Ab, 0, 0, 0);
  stage(Ab, 0, 0, 1);
  stage(Bb, 65536, 0, 0);
  stage(Bb, 65536, 0, 1);
  stage(Ab, 0, 1, 0);
  asm volatile("s_waitcnt vmcnt(2)" ::: "memory");
  __builtin_amdgcn_s_barrier();

  const int pcb = r16 & 7;
  for (int s = 0; s < 12; s++) {
    const int bA = (s & 1) * 32768;
    const int bB = 65536 + (s & 1) * 32768;
    short8 afr[4][2], bfr[4][2];
    // -- phase 0: read A[mh0] + all B; stage A-h1(s+1); MFMA (mh0, nf0-1)
#pragma unroll
    for (int i = 0; i < 4; i++)
#pragma unroll
      for (int kk = 0; kk < 2; kk++)
        afr[i][kk] = *(const short8*)(ldsb + bA +
                         (wm * 128 + i * 16 + r16) * 128 +
                         (((kk * 4 + q4) ^ pcb) << 4));
#pragma unroll
    for (int j = 0; j < 4; j++)
#pragma unroll
      for (int kk = 0; kk < 2; kk++)
        bfr[j][kk] = *(const short8*)(ldsb + bB +
                         (wn * 64 + j * 16 + r16) * 128 +
                         (((kk * 4 + q4) ^ pcb) << 4));
    if (s < 11) stage(Ab, 0, s + 1, 1);
    __builtin_amdgcn_s_barrier();
    __builtin_amdgcn_s_setprio(1);
#pragma unroll
    for (int kk = 0; kk < 2; kk++)
#pragma unroll
      for (int i = 0; i < 4; i++)
#pragma unroll
        for (int j = 0; j < 2; j++)
          acc[i][j] = mfma16(afr[i][kk], bfr[j][kk], acc[i][j]);
    __builtin_amdgcn_s_setprio(0);
    __builtin_amdgcn_s_barrier();
    // -- phase 1: stage B-h0(s+1); MFMA (mh0, nf2-3)
    if (s < 11) stage(Bb, 65536, s + 1, 0);
    __builtin_amdgcn_s_barrier();
    __builtin_amdgcn_s_setprio(1);
#pragma unroll
    for (int kk = 0; kk < 2; kk++)
#pragma unroll
      for (int i = 0; i < 4; i++)
#pragma unroll
        for (int j = 2; j < 4; j++)
          acc[i][j] = mfma16(afr[i][kk], bfr[j][kk], acc[i][j]);
    __builtin_amdgcn_s_setprio(0);
    __builtin_amdgcn_s_barrier();
    // -- phase 2: read A[mh1]; stage B-h1(s+1); MFMA (mh1, nf0-1)
#pragma unroll
    for (int i = 0; i < 4; i++)
#pragma unroll
      for (int kk = 0; kk < 2; kk++)
        afr[i][kk] = *(const short8*)(ldsb + bA +
                         (wm * 128 + (4 + i) * 16 + r16) * 128 +
                         (((kk * 4 + q4) ^ pcb) << 4));
    if (s < 11) stage(Bb, 65536, s + 1, 1);
    __builtin_amdgcn_s_barrier();
    __builtin_amdgcn_s_setprio(1);
#pragma unroll
    for (int kk = 0; kk < 2; kk++)
#pragma unroll
      for (int i = 0; i < 4; i++)
#pragma unroll
        for (int j = 0; j < 2; j++)
          acc[4 + i][j] = mfma16(afr[i][kk], bfr[j][kk], acc[4 + i][j]);
    __builtin_amdgcn_s_setprio(0);
    __builtin_amdgcn_s_barrier();
    // -- phase 3: stage A-h0(s+2) (overwrites cur-buf rows whose reads ended
    //    at phase 2); counted vmcnt(2) -> all of s+1 landed, 2 loads fly.
    if (s < 10) {
      stage(Ab, 0, s + 2, 0);
      asm volatile("s_waitcnt vmcnt(2)" ::: "memory");
    } else if (s == 10) {
      asm volatile("s_waitcnt vmcnt(0)" ::: "memory");
    }
    __builtin_amdgcn_s_barrier();
    __builtin_amdgcn_s_setprio(1);
#pragma unroll
    for (int kk = 0; kk < 2; kk++)
#pragma unroll
      for (int i = 0; i < 4; i++)
#pragma unroll
        for (int j = 2; j < 4; j++)
          acc[4 + i][j] = mfma16(afr[i][kk], bfr[j][kk], acc[4 + i][j]);
    __builtin_amdgcn_s_setprio(0);
    __builtin_amdgcn_s_barrier();
  }

  // epilogue: natural row-major bf16 stores
  const int nb = n0 + wn * 64 + r16;
  float bn[4];
#pragma unroll
  for (int j = 0; j < 4; j++) bn[j] = bias[nb + j * 16];
#pragma unroll
  for (int mf = 0; mf < 8; mf++) {
#pragma unroll
    for (int r = 0; r < 4; r++) {
      int m = m0 + wm * 128 + mf * 16 + q4 * 4 + r;
      u16* cp = Cb + (size_t)m * N + nb;
#pragma unroll
      for (int j = 0; j < 4; j++) cp[j * 16] = f2bf(acc[mf][j][r] + bn[j]);
    }
  }
}

// ---------------- GEMM: C = A[M][K] * Bt[N][K]^T + bias (fp32 out) --------
// 128^2 m97-structure; kept for proj (better granularity at N=768).
__global__ __launch_bounds__(256) void gemm_k(
    const u16* __restrict__ A, const u16* __restrict__ Bt,
    const float* __restrict__ bias, float* __restrict__ Cf,
    int N, int K, int nbx) {
  __shared__ u16 As[128 * 64];
  __shared__ u16 Bs[128 * 64];
  const int tid = threadIdx.x, lane = tid & 63, w = tid >> 6;
  const int r16 = lane & 15, q4 = lane >> 4;
  const int wr = w >> 1, wc = w & 1;
  const int nwg = gridDim.x, cpx = nwg >> 3;
  const int swz = (blockIdx.x & 7) * cpx + (blockIdx.x >> 3);
  const int m0 = (swz / nbx) * 128, n0 = (swz % nbx) * 128;

  f32x4 acc[4][4] = {};

  for (int k0 = 0; k0 < K; k0 += 64) {
#pragma unroll
    for (int g = 0; g < 4; g++) {
      int chunk = (w * 4 + g) * 64 + lane;
      int row = chunk >> 3, p = chunk & 7;
      int gch = p ^ (row & 7);
      gl_lds16(A + (size_t)(m0 + row) * K + k0 + gch * 8, (char*)As + (w * 4 + g) * 1024);
      gl_lds16(Bt + (size_t)(n0 + row) * K + k0 + gch * 8, (char*)Bs + (w * 4 + g) * 1024);
    }
    __syncthreads();
#pragma unroll
    for (int kk = 0; kk < 2; kk++) {
      short8 af[4], bfr[4];
#pragma unroll
      for (int i = 0; i < 4; i++) {
        int row = wr * 64 + i * 16 + r16;
        int pc = (kk * 4 + q4) ^ (r16 & 7);
        af[i] = *(const short8*)((const char*)As + row * 128 + pc * 16);
      }
#pragma unroll
      for (int j = 0; j < 4; j++) {
        int row = wc * 64 + j * 16 + r16;
        int pc = (kk * 4 + q4) ^ (r16 & 7);
        bfr[j] = *(const short8*)((const char*)Bs + row * 128 + pc * 16);
      }
#pragma unroll
      for (int i = 0; i < 4; i++)
#pragma unroll
        for (int j = 0; j < 4; j++) acc[i][j] = mfma16(af[i], bfr[j], acc[i][j]);
    }
    __syncthreads();
  }

  const int nb = n0 + wc * 64 + r16;
  float bn[4];
#pragma unroll
  for (int j = 0; j < 4; j++) bn[j] = bias[nb + j * 16];
#pragma unroll
  for (int i = 0; i < 4; i++) {
#pragma unroll
    for (int r = 0; r < 4; r++) {
      int m = m0 + wr * 64 + i * 16 + q4 * 4 + r;
      float* cp = Cf + (size_t)m * N + nb;
#pragma unroll
      for (int j = 0; j < 4; j++) cp[j * 16] = acc[i][j][r] + bn[j];
    }
  }
}

// ---------------- attention: one block per (b,h) --------------------------
// Swapped QK^T (S^T = mfma(K,Q)) -> P lane-local -> PV via 16x16x16 MFMA.
// No-max softmax; 1/sum deferred to output with row-transposing shuffle.
__global__ __launch_bounds__(256) void attn_k(
    const u16* __restrict__ qkv, const float* __restrict__ be,
    u16* __restrict__ ao) {
  constexpr int VST = 236;
  __shared__ u16 Ks[208 * 32];   // swizzled 16B chunks, rows 0..207
  __shared__ u16 Vt[32 * VST];   // V transposed: Vt[d][n]
  const int tid = threadIdx.x, lane = tid & 63, w = tid >> 6;
  const int r16 = lane & 15, q4 = lane >> 4;
  const int bh = blockIdx.x, b = bh / 24, h = bh % 24;
  const u16* qp = qkv + (size_t)(b * 196) * 2304 + h * 32;
  const u16* kp = qp + 768;
  const u16* vp = qp + 1536;
  const float* bp = be + h * (196 * 208);
  const int ksw = (q4 ^ ((r16 >> 1) & 3)) * 16;
  const float SC2 = 0.17677669529663687f * 1.4426950408889634f;  // 1/sqrt(32)*log2e

  for (int g = w; g < 13; g += 4) {
    int chunk = g * 64 + lane;
    int row = chunk >> 2;
    int gch = (chunk & 3) ^ ((row >> 1) & 3);
    gl_lds16(kp + (size_t)row * 2304 + gch * 8, (char*)Ks + g * 1024);
  }
  for (int c = tid; c < 784; c += 256) {
    int n = c >> 2, d0 = (c & 3) * 8;
    u16x8 vv = *(const u16x8*)(vp + (size_t)n * 2304 + (c & 3) * 8);
#pragma unroll
    for (int jj = 0; jj < 8; jj++) Vt[(d0 + jj) * VST + n] = vv[jj];
  }
  for (int idx = tid; idx < 32 * 40; idx += 256) {
    int d = idx / 40, n = 196 + idx % 40;
    Vt[d * VST + n] = 0;
  }
  __syncthreads();

  const f32x4 z = {0.f, 0.f, 0.f, 0.f};
  short8 bq = *(const short8*)(qp + (size_t)(w * 16 + r16) * 2304 + q4 * 8);
  for (int si = w; si < 13; si += 4) {
    short8 bq_next = {};
    if (si + 4 < 13)
      bq_next = *(const short8*)(qp + (size_t)((si + 4) * 16 + r16) * 2304 + q4 * 8);
    int gc = si * 16 + r16;
    gc = gc < 196 ? gc : 195;
    const float* brow = bp + gc * 208 + q4 * 4;
    float s0 = 0.f, s1 = 0.f, s2 = 0.f, s3 = 0.f;
    short4v pa[13];
#pragma unroll
    for (int t = 0; t < 13; t++) {
      short8 ka = *(const short8*)((const char*)Ks + (t * 16 + r16) * 64 + ksw);
      f32x4 p = mfma16(ka, bq, z);
      float4 bv = *(const float4*)(brow + t * 16);
      float e0 = __builtin_amdgcn_exp2f(p[0] * SC2 + bv.x);
      float e1 = __builtin_amdgcn_exp2f(p[1] * SC2 + bv.y);
      float e2 = __builtin_amdgcn_exp2f(p[2] * SC2 + bv.z);
      float e3 = __builtin_amdgcn_exp2f(p[3] * SC2 + bv.w);
      if (t == 12) {
        int k0 = 192 + q4 * 4;
        e0 = (k0 + 0 < 196) ? e0 : 0.f;
        e1 = (k0 + 1 < 196) ? e1 : 0.f;
        e2 = (k0 + 2 < 196) ? e2 : 0.f;
        e3 = (k0 + 3 < 196) ? e3 : 0.f;
      }
      s0 += e0; s1 += e1; s2 += e2; s3 += e3;
      pa[t][0] = (short)f2bf(e0);
      pa[t][1] = (short)f2bf(e1);
      pa[t][2] = (short)f2bf(e2);
      pa[t][3] = (short)f2bf(e3);
    }
    bq = bq_next;
    float sum = (s0 + s1) + (s2 + s3);
    sum += __shfl_xor(sum, 16, 64);
    sum += __shfl_xor(sum, 32, 64);
    float rs = 1.0f / sum;
    f32x4 o0a = z, o0b = z, o1a = z, o1b = z;
    __builtin_amdgcn_s_setprio(1);
#pragma unroll
    for (int t = 0; t < 13; t++) {
      const u16* vrow = &Vt[r16 * VST + t * 16 + q4 * 4];
      short4v b0 = *(const short4v*)vrow;
      short4v b1 = *(const short4v*)(vrow + 16 * VST);
      if (t & 1) {
        o0b = mfma16x16(pa[t], b0, o0b);
        o1b = mfma16x16(pa[t], b1, o1b);
      } else {
        o0a = mfma16x16(pa[t], b0, o0a);
        o1a = mfma16x16(pa[t], b1, o1a);
      }
    }
    __builtin_amdgcn_s_setprio(0);
#pragma unroll
    for (int r = 0; r < 4; r++) {
      float rsv = __shfl(rs, q4 * 4 + r, 16);
      int grow = si * 16 + q4 * 4 + r;
      if (grow < 196) {
        u16* op = ao + ((size_t)(b * 196 + grow)) * 768 + h * 32;
        op[r16] = f2bf((o0a[r] + o0b[r]) * rsv);
        op[16 + r16] = f2bf((o1a[r] + o1b[r]) * rsv);
      }
    }
  }
}

// ---------------------------------------------------------------------------
extern "C" void kernel_launch(void* const* d_in, const int* in_sizes, int n_in,
                              void* d_out, int out_size, void* d_ws, size_t ws_size,
                              hipStream_t stream) {
  const float* x = (const float*)d_in[0];
  const float* qkv_w = (const float*)d_in[1];
  const float* qkv_b = (const float*)d_in[2];
  const float* proj_w = (const float*)d_in[3];
  const float* proj_b = (const float*)d_in[4];
  const float* cpb_w1 = (const float*)d_in[5];
  const float* cpb_b1 = (const float*)d_in[6];
  const float* cpb_w2 = (const float*)d_in[7];
  const float* cpb_b2 = (const float*)d_in[8];
  float* out = (float*)d_out;

  char* ws = (char*)d_ws;
  size_t o = 0;
  auto alloc = [&](size_t sz) {
    size_t r = o;
    o = (o + sz + 255) & ~(size_t)255;
    return r;
  };
  const size_t ME = (size_t)25088 * 768;  // elems per [B,N,DIM]-sized tensor
  u16* x_bf = (u16*)(ws + alloc(ME * 2));           // also aliased as attnout
  u16* wq_t = (u16*)(ws + alloc((size_t)2304 * 768 * 2));
  u16* wp_t = (u16*)(ws + alloc((size_t)768 * 768 * 2));
  u16* qkv_s = (u16*)(ws + alloc(3 * ME * 2));      // [25088][2304] bf16
  float* btab = (float*)(ws + alloc((size_t)729 * 24 * 4));
  float* bexp = (float*)(ws + alloc((size_t)24 * 196 * 208 * 4));
  u16* ao = x_bf;  // alias: x_bf dead after qkv GEMM

  cvt_x_k<<<18816, 256, 0, stream>>>(x, x_bf);
  cvt_wt_k<<<6912, 256, 0, stream>>>(qkv_w, wq_t, 2304);
  cvt_wt_k<<<2304, 256, 0, stream>>>(proj_w, wp_t, 768);
  bias_mlp_k<<<729, 64, 0, stream>>>(cpb_w1, cpb_b1, cpb_w2, cpb_b2, btab);
  bias_expand_k<<<3822, 256, 0, stream>>>(btab, bexp);
  gemm256_k<<<882, 512, 0, stream>>>(x_bf, wq_t, qkv_b, qkv_s, 2304, 9);
  attn_k<<<3072, 256, 0, stream>>>(qkv_s, bexp, ao);
  gemm_k<<<1176, 256, 0, stream>>>(ao, wp_t, proj_b, out, 768, 768, 6);
}

// Round 12
// 272.866 us; speedup vs baseline: 1.0581x; 1.0405x over previous
//
#include <hip/hip_runtime.h>
#include <hip/hip_bf16.h>

typedef unsigned short u16;
typedef __attribute__((ext_vector_type(8))) short short8;
typedef __attribute__((ext_vector_type(4))) short short4v;
typedef __attribute__((ext_vector_type(8))) u16 u16x8;
typedef __attribute__((ext_vector_type(4))) u16 u16x4;
typedef __attribute__((ext_vector_type(4))) float f32x4;

__device__ __forceinline__ u16 f2bf(float f) {
  __hip_bfloat16 h = __float2bfloat16(f);
  u16 u;
  __builtin_memcpy(&u, &h, 2);
  return u;
}

__device__ __forceinline__ f32x4 mfma16(short8 a, short8 b, f32x4 c) {
  return __builtin_amdgcn_mfma_f32_16x16x32_bf16(a, b, c, 0, 0, 0);
}

__device__ __forceinline__ f32x4 mfma16x16(short4v a, short4v b, f32x4 c) {
#if __has_builtin(__builtin_amdgcn_mfma_f32_16x16x16bf16_1k)
  return __builtin_amdgcn_mfma_f32_16x16x16bf16_1k(a, b, c, 0, 0, 0);
#else
  asm("v_mfma_f32_16x16x16_bf16 %0, %1, %2, %0" : "+v"(c) : "v"(a), "v"(b));
  return c;
#endif
}

__device__ __forceinline__ void gl_lds16(const void* g, void* l) {
  __builtin_amdgcn_global_load_lds(
      (const __attribute__((address_space(1))) unsigned int*)g,
      (__attribute__((address_space(3))) unsigned int*)l, 16, 0, 0);
}

// ---------------- convert x fp32 -> bf16 ----------------
__global__ __launch_bounds__(256) void cvt_x_k(const float* __restrict__ x,
                                               u16* __restrict__ xb) {
  int i = (blockIdx.x * 256 + threadIdx.x) * 4;
  float4 v = *(const float4*)(x + i);
  u16x4 o = { f2bf(v.x), f2bf(v.y), f2bf(v.z), f2bf(v.w) };
  *(u16x4*)(xb + i) = o;
}

// ------- transpose + convert weight via LDS tile: wt[n][k] = w[k][n] -------
// grid (N/64, K/64=12); both global phases coalesced.
__global__ __launch_bounds__(256) void cvt_wt_k(const float* __restrict__ w,
                                                u16* __restrict__ wt, int N) {
  __shared__ u16 t64[64][65];
  const int n0 = blockIdx.x * 64, k0 = blockIdx.y * 64;
  const int c = threadIdx.x & 63, rg = threadIdx.x >> 6;
#pragma unroll
  for (int r = 0; r < 16; r++) {
    int kk = rg * 16 + r;
    t64[c][kk] = f2bf(w[(size_t)(k0 + kk) * N + n0 + c]);
  }
  __syncthreads();
#pragma unroll
  for (int r = 0; r < 16; r++) {
    int nn = rg * 16 + r;
    wt[(size_t)(n0 + nn) * 768 + k0 + c] = t64[nn][c];
  }
}

// ---------------- CPB bias MLP: 729 entries x (2->512->24), 16*sigmoid -----
__device__ __forceinline__ float cpb_coord(int v) {
  float c = (float)(v - 13) * (8.0f / 13.0f);
  float a = fabsf(c);
  float r = log2f(a + 1.0f) * (1.0f / 3.0f);
  return c < 0.f ? -r : r;
}

__global__ __launch_bounds__(64) void bias_mlp_k(
    const float* __restrict__ w1, const float* __restrict__ b1,
    const float* __restrict__ w2, const float* __restrict__ b2,
    float* __restrict__ btab) {
  int e = blockIdx.x;
  int lane = threadIdx.x;
  float t0 = cpb_coord(e / 27), t1 = cpb_coord(e % 27);
  float acc[24];
#pragma unroll
  for (int hh = 0; hh < 24; hh++) acc[hh] = 0.f;
#pragma unroll
  for (int jj = 0; jj < 8; jj++) {
    int j = lane * 8 + jj;
    float h1 = t0 * w1[j] + t1 * w1[512 + j] + b1[j];
    h1 = fmaxf(h1, 0.f);
#pragma unroll
    for (int hh = 0; hh < 24; hh++) acc[hh] += h1 * w2[j * 24 + hh];
  }
#pragma unroll
  for (int hh = 0; hh < 24; hh++)
#pragma unroll
    for (int m = 1; m < 64; m <<= 1) acc[hh] += __shfl_xor(acc[hh], m, 64);
  if (lane == 0) {
#pragma unroll
    for (int hh = 0; hh < 24; hh++) {
      float v = acc[hh] + b2[hh];
      btab[e * 24 + hh] = 16.f / (1.f + __expf(-v));
    }
  }
}

// ---------------- expand bias to [24][196][208] fp32, pre-scaled by log2e --
__global__ __launch_bounds__(256) void bias_expand_k(const float* __restrict__ tab,
                                                     float* __restrict__ be) {
  int i = blockIdx.x * 256 + threadIdx.x;  // 24*196*208
  int h = i / (196 * 208);
  int rem = i % (196 * 208);
  int row = rem / 208, col = rem % 208;
  float v = 0.f;
  if (col < 196) {
    int dy = row / 14 - col / 14 + 13;
    int dx = row % 14 - col % 14 + 13;
    v = tab[(dy * 27 + dx) * 24 + h] * 1.4426950408889634f;
  }
  be[i] = v;
}

// ---------------- 256x256 8-wave 4-phase pipelined GEMM (K=768) ------------
// 2-K-step-deep prefetch, 2 LDS buffers. RACE FIX vs R8/R11: the wave M-split
// means A-h0 is read at ph0 (rows 0-63) AND ph2 (rows 64-127) by wm=0 waves
// (A-h1 likewise by wm=1), so A is only dead after ph2's trailing barrier.
// B IS fully read in ph0 (4 wn groups cover rows 0..255). Staging into the
// current buffer: ph1: B-h0(s+2); ph2: B-h1(s+2); ph3: A-h0+A-h1(s+2), then
// counted vmcnt(8) (= this step's 8 loads in flight; s+1 fully landed).
__global__ __launch_bounds__(512) void gemm256_k(
    const u16* __restrict__ A, const u16* __restrict__ Bt,
    const float* __restrict__ bias, u16* __restrict__ Cb, int N, int nbx) {
  __shared__ u16 lds[65536];  // 128 KiB
  char* ldsb = (char*)lds;
  const int tid = threadIdx.x, lane = tid & 63, w = tid >> 6;
  const int r16 = lane & 15, q4 = lane >> 4;
  const int wm = w >> 2, wn = w & 3;
  const int nwg = gridDim.x;
  const int qq = nwg >> 3, rr = nwg & 7;
  const int xcd = blockIdx.x & 7, bidx = blockIdx.x >> 3;
  const int swz = (xcd < rr) ? xcd * (qq + 1) + bidx
                             : rr * (qq + 1) + (xcd - rr) * qq + bidx;
  const int m0 = (swz / nbx) * 256, n0 = (swz % nbx) * 256;
  const u16* Ab = A + (size_t)m0 * 768;
  const u16* Bb = Bt + (size_t)n0 * 768;

  auto stage = [&](const u16* __restrict__ src, int matBase, int sdst, int h) {
    char* base = ldsb + matBase + (sdst & 1) * 32768 + h * 16384 + w * 1024;
    const int k0 = sdst * 64;
#pragma unroll
    for (int g = 0; g < 2; g++) {
      int c = g * 512 + tid;
      int row = c >> 3, p = c & 7;
      int gch = p ^ (row & 7);
      gl_lds16(src + (size_t)(h * 128 + row) * 768 + k0 + gch * 8,
               base + g * 8192 + lane * 16);
    }
  };

  f32x4 acc[8][4] = {};

  // prologue: stage K-steps 0 and 1 fully (16 loads); vmcnt(8) -> s0 landed.
  stage(Ab, 0, 0, 0);
  stage(Ab, 0, 0, 1);
  stage(Bb, 65536, 0, 0);
  stage(Bb, 65536, 0, 1);
  stage(Ab, 0, 1, 0);
  stage(Ab, 0, 1, 1);
  stage(Bb, 65536, 1, 0);
  stage(Bb, 65536, 1, 1);
  asm volatile("s_waitcnt vmcnt(8)" ::: "memory");
  __builtin_amdgcn_s_barrier();

  const int pcb = r16 & 7;
  for (int s = 0; s < 12; s++) {
    const int bA = (s & 1) * 32768;
    const int bB = 65536 + (s & 1) * 32768;
    const bool pf = (s < 10);
    short8 afr[4][2], bfr[4][2];
    // -- phase 0: read A[mh-first-half] + all B (16 ds_read); MFMA
#pragma unroll
    for (int i = 0; i < 4; i++)
#pragma unroll
      for (int kk = 0; kk < 2; kk++)
        afr[i][kk] = *(const short8*)(ldsb + bA +
                         (wm * 128 + i * 16 + r16) * 128 +
                         (((kk * 4 + q4) ^ pcb) << 4));
#pragma unroll
    for (int j = 0; j < 4; j++)
#pragma unroll
      for (int kk = 0; kk < 2; kk++)
        bfr[j][kk] = *(const short8*)(ldsb + bB +
                         (wn * 64 + j * 16 + r16) * 128 +
                         (((kk * 4 + q4) ^ pcb) << 4));
    __builtin_amdgcn_s_barrier();
    __builtin_amdgcn_s_setprio(1);
#pragma unroll
    for (int kk = 0; kk < 2; kk++)
#pragma unroll
      for (int i = 0; i < 4; i++)
#pragma unroll
        for (int j = 0; j < 2; j++)
          acc[i][j] = mfma16(afr[i][kk], bfr[j][kk], acc[i][j]);
    __builtin_amdgcn_s_setprio(0);
    __builtin_amdgcn_s_barrier();
    // -- phase 1: stage B-h0(s+2) (B-cur dead after ph0); MFMA
    if (pf) stage(Bb, 65536, s + 2, 0);
    __builtin_amdgcn_s_barrier();
    __builtin_amdgcn_s_setprio(1);
#pragma unroll
    for (int kk = 0; kk < 2; kk++)
#pragma unroll
      for (int i = 0; i < 4; i++)
#pragma unroll
        for (int j = 2; j < 4; j++)
          acc[i][j] = mfma16(afr[i][kk], bfr[j][kk], acc[i][j]);
    __builtin_amdgcn_s_setprio(0);
    __builtin_amdgcn_s_barrier();
    // -- phase 2: read A[mh-second-half]; stage B-h1(s+2); MFMA
#pragma unroll
    for (int i = 0; i < 4; i++)
#pragma unroll
      for (int kk = 0; kk < 2; kk++)
        afr[i][kk] = *(const short8*)(ldsb + bA +
                         (wm * 128 + (4 + i) * 16 + r16) * 128 +
                         (((kk * 4 + q4) ^ pcb) << 4));
    if (pf) stage(Bb, 65536, s + 2, 1);
    __builtin_amdgcn_s_barrier();
    __builtin_amdgcn_s_setprio(1);
#pragma unroll
    for (int kk = 0; kk < 2; kk++)
#pragma unroll
      for (int i = 0; i < 4; i++)
#pragma unroll
        for (int j = 0; j < 2; j++)
          acc[4 + i][j] = mfma16(afr[i][kk], bfr[j][kk], acc[4 + i][j]);
    __builtin_amdgcn_s_setprio(0);
    __builtin_amdgcn_s_barrier();
    // -- phase 3: stage A-h0+A-h1(s+2) (A-cur dead after ph2's barrier);
    //    counted vmcnt(8) = this step's 8 loads in flight, s+1 landed.
    if (pf) {
      stage(Ab, 0, s + 2, 0);
      stage(Ab, 0, s + 2, 1);
      asm volatile("s_waitcnt vmcnt(8)" ::: "memory");
    } else if (s == 10) {
      asm volatile("s_waitcnt vmcnt(0)" ::: "memory");
    }
    __builtin_amdgcn_s_barrier();
    __builtin_amdgcn_s_setprio(1);
#pragma unroll
    for (int kk = 0; kk < 2; kk++)
#pragma unroll
      for (int i = 0; i < 4; i++)
#pragma unroll
        for (int j = 2; j < 4; j++)
          acc[4 + i][j] = mfma16(afr[i][kk], bfr[j][kk], acc[4 + i][j]);
    __builtin_amdgcn_s_setprio(0);
    __builtin_amdgcn_s_barrier();
  }

  // epilogue: natural row-major bf16 stores
  const int nb = n0 + wn * 64 + r16;
  float bn[4];
#pragma unroll
  for (int j = 0; j < 4; j++) bn[j] = bias[nb + j * 16];
#pragma unroll
  for (int mf = 0; mf < 8; mf++) {
#pragma unroll
    for (int r = 0; r < 4; r++) {
      int m = m0 + wm * 128 + mf * 16 + q4 * 4 + r;
      u16* cp = Cb + (size_t)m * N + nb;
#pragma unroll
      for (int j = 0; j < 4; j++) cp[j * 16] = f2bf(acc[mf][j][r] + bn[j]);
    }
  }
}

// ---------------- GEMM: C = A[M][K] * Bt[N][K]^T + bias (fp32 out) --------
// 128^2 m97-structure; kept for proj.
__global__ __launch_bounds__(256) void gemm_k(
    const u16* __restrict__ A, const u16* __restrict__ Bt,
    const float* __restrict__ bias, float* __restrict__ Cf,
    int N, int K, int nbx) {
  __shared__ u16 As[128 * 64];
  __shared__ u16 Bs[128 * 64];
  const int tid = threadIdx.x, lane = tid & 63, w = tid >> 6;
  const int r16 = lane & 15, q4 = lane >> 4;
  const int wr = w >> 1, wc = w & 1;
  const int nwg = gridDim.x, cpx = nwg >> 3;
  const int swz = (blockIdx.x & 7) * cpx + (blockIdx.x >> 3);
  const int m0 = (swz / nbx) * 128, n0 = (swz % nbx) * 128;

  f32x4 acc[4][4] = {};

  for (int k0 = 0; k0 < K; k0 += 64) {
#pragma unroll
    for (int g = 0; g < 4; g++) {
      int chunk = (w * 4 + g) * 64 + lane;
      int row = chunk >> 3, p = chunk & 7;
      int gch = p ^ (row & 7);
      gl_lds16(A + (size_t)(m0 + row) * K + k0 + gch * 8, (char*)As + (w * 4 + g) * 1024);
      gl_lds16(Bt + (size_t)(n0 + row) * K + k0 + gch * 8, (char*)Bs + (w * 4 + g) * 1024);
    }
    __syncthreads();
#pragma unroll
    for (int kk = 0; kk < 2; kk++) {
      short8 af[4], bfr[4];
#pragma unroll
      for (int i = 0; i < 4; i++) {
        int row = wr * 64 + i * 16 + r16;
        int pc = (kk * 4 + q4) ^ (r16 & 7);
        af[i] = *(const short8*)((const char*)As + row * 128 + pc * 16);
      }
#pragma unroll
      for (int j = 0; j < 4; j++) {
        int row = wc * 64 + j * 16 + r16;
        int pc = (kk * 4 + q4) ^ (r16 & 7);
        bfr[j] = *(const short8*)((const char*)Bs + row * 128 + pc * 16);
      }
#pragma unroll
      for (int i = 0; i < 4; i++)
#pragma unroll
        for (int j = 0; j < 4; j++) acc[i][j] = mfma16(af[i], bfr[j], acc[i][j]);
    }
    __syncthreads();
  }

  const int nb = n0 + wc * 64 + r16;
  float bn[4];
#pragma unroll
  for (int j = 0; j < 4; j++) bn[j] = bias[nb + j * 16];
#pragma unroll
  for (int i = 0; i < 4; i++) {
#pragma unroll
    for (int r = 0; r < 4; r++) {
      int m = m0 + wr * 64 + i * 16 + q4 * 4 + r;
      float* cp = Cf + (size_t)m * N + nb;
#pragma unroll
      for (int j = 0; j < 4; j++) cp[j * 16] = acc[i][j][r] + bn[j];
    }
  }
}

// ---------------- attention: one block per (b,h) --------------------------
// Swapped QK^T -> P lane-local -> PV via 16x16x16 MFMA. No-max softmax;
// 1/sum deferred with row-transposing shuffle. (Last-passing R8 version,
// fp32 bias loads inside the fused loop.)
__global__ __launch_bounds__(256) void attn_k(
    const u16* __restrict__ qkv, const float* __restrict__ be,
    u16* __restrict__ ao) {
  constexpr int VST = 236;
  __shared__ u16 Ks[208 * 32];
  __shared__ u16 Vt[32 * VST];
  const int tid = threadIdx.x, lane = tid & 63, w = tid >> 6;
  const int r16 = lane & 15, q4 = lane >> 4;
  const int bh = blockIdx.x, b = bh / 24, h = bh % 24;
  const u16* qp = qkv + (size_t)(b * 196) * 2304 + h * 32;
  const u16* kp = qp + 768;
  const u16* vp = qp + 1536;
  const float* bp = be + h * (196 * 208);
  const int ksw = (q4 ^ ((r16 >> 1) & 3)) * 16;
  const float SC2 = 0.17677669529663687f * 1.4426950408889634f;

  for (int g = w; g < 13; g += 4) {
    int chunk = g * 64 + lane;
    int row = chunk >> 2;
    int gch = (chunk & 3) ^ ((row >> 1) & 3);
    gl_lds16(kp + (size_t)row * 2304 + gch * 8, (char*)Ks + g * 1024);
  }
  for (int c = tid; c < 784; c += 256) {
    int n = c >> 2, d0 = (c & 3) * 8;
    u16x8 vv = *(const u16x8*)(vp + (size_t)n * 2304 + (c & 3) * 8);
#pragma unroll
    for (int jj = 0; jj < 8; jj++) Vt[(d0 + jj) * VST + n] = vv[jj];
  }
  for (int idx = tid; idx < 32 * 40; idx += 256) {
    int d = idx / 40, n = 196 + idx % 40;
    Vt[d * VST + n] = 0;
  }
  __syncthreads();

  const f32x4 z = {0.f, 0.f, 0.f, 0.f};
  short8 bq = *(const short8*)(qp + (size_t)(w * 16 + r16) * 2304 + q4 * 8);
  for (int si = w; si < 13; si += 4) {
    short8 bq_next = {};
    if (si + 4 < 13)
      bq_next = *(const short8*)(qp + (size_t)((si + 4) * 16 + r16) * 2304 + q4 * 8);
    int gc = si * 16 + r16;
    gc = gc < 196 ? gc : 195;
    const float* brow = bp + gc * 208 + q4 * 4;
    float s0 = 0.f, s1 = 0.f, s2 = 0.f, s3 = 0.f;
    short4v pa[13];
#pragma unroll
    for (int t = 0; t < 13; t++) {
      short8 ka = *(const short8*)((const char*)Ks + (t * 16 + r16) * 64 + ksw);
      f32x4 p = mfma16(ka, bq, z);
      float4 bv = *(const float4*)(brow + t * 16);
      float e0 = __builtin_amdgcn_exp2f(p[0] * SC2 + bv.x);
      float e1 = __builtin_amdgcn_exp2f(p[1] * SC2 + bv.y);
      float e2 = __builtin_amdgcn_exp2f(p[2] * SC2 + bv.z);
      float e3 = __builtin_amdgcn_exp2f(p[3] * SC2 + bv.w);
      if (t == 12) {
        int k0 = 192 + q4 * 4;
        e0 = (k0 + 0 < 196) ? e0 : 0.f;
        e1 = (k0 + 1 < 196) ? e1 : 0.f;
        e2 = (k0 + 2 < 196) ? e2 : 0.f;
        e3 = (k0 + 3 < 196) ? e3 : 0.f;
      }
      s0 += e0; s1 += e1; s2 += e2; s3 += e3;
      pa[t][0] = (short)f2bf(e0);
      pa[t][1] = (short)f2bf(e1);
      pa[t][2] = (short)f2bf(e2);
      pa[t][3] = (short)f2bf(e3);
    }
    bq = bq_next;
    float sum = (s0 + s1) + (s2 + s3);
    sum += __shfl_xor(sum, 16, 64);
    sum += __shfl_xor(sum, 32, 64);
    float rs = 1.0f / sum;
    f32x4 o0a = z, o0b = z, o1a = z, o1b = z;
    __builtin_amdgcn_s_setprio(1);
#pragma unroll
    for (int t = 0; t < 13; t++) {
      const u16* vrow = &Vt[r16 * VST + t * 16 + q4 * 4];
      short4v b0 = *(const short4v*)vrow;
      short4v b1 = *(const short4v*)(vrow + 16 * VST);
      if (t & 1) {
        o0b = mfma16x16(pa[t], b0, o0b);
        o1b = mfma16x16(pa[t], b1, o1b);
      } else {
        o0a = mfma16x16(pa[t], b0, o0a);
        o1a = mfma16x16(pa[t], b1, o1a);
      }
    }
    __builtin_amdgcn_s_setprio(0);
#pragma unroll
    for (int r = 0; r < 4; r++) {
      float rsv = __shfl(rs, q4 * 4 + r, 16);
      int grow = si * 16 + q4 * 4 + r;
      if (grow < 196) {
        u16* op = ao + ((size_t)(b * 196 + grow)) * 768 + h * 32;
        op[r16] = f2bf((o0a[r] + o0b[r]) * rsv);
        op[16 + r16] = f2bf((o1a[r] + o1b[r]) * rsv);
      }
    }
  }
}

// ---------------------------------------------------------------------------
extern "C" void kernel_launch(void* const* d_in, const int* in_sizes, int n_in,
                              void* d_out, int out_size, void* d_ws, size_t ws_size,
                              hipStream_t stream) {
  const float* x = (const float*)d_in[0];
  const float* qkv_w = (const float*)d_in[1];
  const float* qkv_b = (const float*)d_in[2];
  const float* proj_w = (const float*)d_in[3];
  const float* proj_b = (const float*)d_in[4];
  const float* cpb_w1 = (const float*)d_in[5];
  const float* cpb_b1 = (const float*)d_in[6];
  const float* cpb_w2 = (const float*)d_in[7];
  const float* cpb_b2 = (const float*)d_in[8];
  float* out = (float*)d_out;

  char* ws = (char*)d_ws;
  size_t o = 0;
  auto alloc = [&](size_t sz) {
    size_t r = o;
    o = (o + sz + 255) & ~(size_t)255;
    return r;
  };
  const size_t ME = (size_t)25088 * 768;
  u16* x_bf = (u16*)(ws + alloc(ME * 2));           // also aliased as attnout
  u16* wq_t = (u16*)(ws + alloc((size_t)2304 * 768 * 2));
  u16* wp_t = (u16*)(ws + alloc((size_t)768 * 768 * 2));
  u16* qkv_s = (u16*)(ws + alloc(3 * ME * 2));      // [25088][2304] bf16
  float* btab = (float*)(ws + alloc((size_t)729 * 24 * 4));
  float* bexp = (float*)(ws + alloc((size_t)24 * 196 * 208 * 4));
  u16* ao = x_bf;

  cvt_x_k<<<18816, 256, 0, stream>>>(x, x_bf);
  cvt_wt_k<<<dim3(36, 12), 256, 0, stream>>>(qkv_w, wq_t, 2304);
  cvt_wt_k<<<dim3(12, 12), 256, 0, stream>>>(proj_w, wp_t, 768);
  bias_mlp_k<<<729, 64, 0, stream>>>(cpb_w1, cpb_b1, cpb_w2, cpb_b2, btab);
  bias_expand_k<<<3822, 256, 0, stream>>>(btab, bexp);
  gemm256_k<<<882, 512, 0, stream>>>(x_bf, wq_t, qkv_b, qkv_s, 2304, 9);
  attn_k<<<3072, 256, 0, stream>>>(qkv_s, bexp, ao);
  gemm_k<<<1176, 256, 0, stream>>>(ao, wp_t, proj_b, out, 768, 768, 6);
}

// Round 13
// 269.866 us; speedup vs baseline: 1.0699x; 1.0111x over previous
//
#include <hip/hip_runtime.h>
#include <hip/hip_bf16.h>

typedef unsigned short u16;
typedef __attribute__((ext_vector_type(8))) short short8;
typedef __attribute__((ext_vector_type(4))) short short4v;
typedef __attribute__((ext_vector_type(8))) u16 u16x8;
typedef __attribute__((ext_vector_type(4))) u16 u16x4;
typedef __attribute__((ext_vector_type(4))) float f32x4;

__device__ __forceinline__ u16 f2bf(float f) {
  __hip_bfloat16 h = __float2bfloat16(f);
  u16 u;
  __builtin_memcpy(&u, &h, 2);
  return u;
}

__device__ __forceinline__ float h2f(u16 h) {
  return (float)__builtin_bit_cast(_Float16, h);
}

__device__ __forceinline__ f32x4 mfma16(short8 a, short8 b, f32x4 c) {
  return __builtin_amdgcn_mfma_f32_16x16x32_bf16(a, b, c, 0, 0, 0);
}

__device__ __forceinline__ f32x4 mfma16x16(short4v a, short4v b, f32x4 c) {
#if __has_builtin(__builtin_amdgcn_mfma_f32_16x16x16bf16_1k)
  return __builtin_amdgcn_mfma_f32_16x16x16bf16_1k(a, b, c, 0, 0, 0);
#else
  asm("v_mfma_f32_16x16x16_bf16 %0, %1, %2, %0" : "+v"(c) : "v"(a), "v"(b));
  return c;
#endif
}

__device__ __forceinline__ void gl_lds16(const void* g, void* l) {
  __builtin_amdgcn_global_load_lds(
      (const __attribute__((address_space(1))) unsigned int*)g,
      (__attribute__((address_space(3))) unsigned int*)l, 16, 0, 0);
}

// ---------------- convert x fp32 -> bf16 ----------------
__global__ __launch_bounds__(256) void cvt_x_k(const float* __restrict__ x,
                                               u16* __restrict__ xb) {
  int i = (blockIdx.x * 256 + threadIdx.x) * 4;
  float4 v = *(const float4*)(x + i);
  u16x4 o = { f2bf(v.x), f2bf(v.y), f2bf(v.z), f2bf(v.w) };
  *(u16x4*)(xb + i) = o;
}

// ------- transpose + convert weight via LDS tile: wt[n][k] = w[k][n] -------
__global__ __launch_bounds__(256) void cvt_wt_k(const float* __restrict__ w,
                                                u16* __restrict__ wt, int N) {
  __shared__ u16 t64[64][65];
  const int n0 = blockIdx.x * 64, k0 = blockIdx.y * 64;
  const int c = threadIdx.x & 63, rg = threadIdx.x >> 6;
#pragma unroll
  for (int r = 0; r < 16; r++) {
    int kk = rg * 16 + r;
    t64[c][kk] = f2bf(w[(size_t)(k0 + kk) * N + n0 + c]);
  }
  __syncthreads();
#pragma unroll
  for (int r = 0; r < 16; r++) {
    int nn = rg * 16 + r;
    wt[(size_t)(n0 + nn) * 768 + k0 + c] = t64[nn][c];
  }
}

// ---------------- CPB bias MLP: 729 entries x (2->512->24), 16*sigmoid -----
__device__ __forceinline__ float cpb_coord(int v) {
  float c = (float)(v - 13) * (8.0f / 13.0f);
  float a = fabsf(c);
  float r = log2f(a + 1.0f) * (1.0f / 3.0f);
  return c < 0.f ? -r : r;
}

__global__ __launch_bounds__(64) void bias_mlp_k(
    const float* __restrict__ w1, const float* __restrict__ b1,
    const float* __restrict__ w2, const float* __restrict__ b2,
    float* __restrict__ btab) {
  int e = blockIdx.x;
  int lane = threadIdx.x;
  float t0 = cpb_coord(e / 27), t1 = cpb_coord(e % 27);
  float acc[24];
#pragma unroll
  for (int hh = 0; hh < 24; hh++) acc[hh] = 0.f;
#pragma unroll
  for (int jj = 0; jj < 8; jj++) {
    int j = lane * 8 + jj;
    float h1 = t0 * w1[j] + t1 * w1[512 + j] + b1[j];
    h1 = fmaxf(h1, 0.f);
#pragma unroll
    for (int hh = 0; hh < 24; hh++) acc[hh] += h1 * w2[j * 24 + hh];
  }
#pragma unroll
  for (int hh = 0; hh < 24; hh++)
#pragma unroll
    for (int m = 1; m < 64; m <<= 1) acc[hh] += __shfl_xor(acc[hh], m, 64);
  if (lane == 0) {
#pragma unroll
    for (int hh = 0; hh < 24; hh++) {
      float v = acc[hh] + b2[hh];
      btab[e * 24 + hh] = 16.f / (1.f + __expf(-v));
    }
  }
}

// --------- expand bias to [24][196][208] f16 bits, pre-scaled by log2e -----
// f16 arg error <= ~0.008 in the exponent (arg <= 23.1) -> <=0.6% relative on
// softmax weights, mostly common-mode. Halves hoisted-bias VGPR cost in attn.
__global__ __launch_bounds__(256) void bias_expand_k(const float* __restrict__ tab,
                                                     u16* __restrict__ be) {
  int i = blockIdx.x * 256 + threadIdx.x;  // 24*196*208
  int h = i / (196 * 208);
  int rem = i % (196 * 208);
  int row = rem / 208, col = rem % 208;
  float v = 0.f;
  if (col < 196) {
    int dy = row / 14 - col / 14 + 13;
    int dx = row % 14 - col % 14 + 13;
    v = tab[(dy * 27 + dx) * 24 + h] * 1.4426950408889634f;
  }
  _Float16 hv = (_Float16)v;
  be[i] = __builtin_bit_cast(unsigned short, hv);
}

// ---------------- GEMM: C = A[M][K] * Bt[N][K]^T + bias -------------------
// 128^2 m97-structure (verified 111.5us / 35% MfmaUtil on qkv). The 256^2
// 4-phase pipeline was tried (R8/R11/R12) and never beat this: barrier-bound
// at 1 block/CU, not load-latency-bound. EPI=0: bf16 out; EPI=1: fp32 out.
template <int EPI>
__global__ __launch_bounds__(256) void gemm_k(
    const u16* __restrict__ A, const u16* __restrict__ Bt,
    const float* __restrict__ bias, float* __restrict__ Cf,
    u16* __restrict__ Cb, int N, int K, int nbx) {
  __shared__ u16 As[128 * 64];
  __shared__ u16 Bs[128 * 64];
  const int tid = threadIdx.x, lane = tid & 63, w = tid >> 6;
  const int r16 = lane & 15, q4 = lane >> 4;
  const int wr = w >> 1, wc = w & 1;
  const int nwg = gridDim.x, cpx = nwg >> 3;
  const int swz = (blockIdx.x & 7) * cpx + (blockIdx.x >> 3);
  const int m0 = (swz / nbx) * 128, n0 = (swz % nbx) * 128;

  f32x4 acc[4][4] = {};

  for (int k0 = 0; k0 < K; k0 += 64) {
#pragma unroll
    for (int g = 0; g < 4; g++) {
      int chunk = (w * 4 + g) * 64 + lane;
      int row = chunk >> 3, p = chunk & 7;
      int gch = p ^ (row & 7);
      gl_lds16(A + (size_t)(m0 + row) * K + k0 + gch * 8, (char*)As + (w * 4 + g) * 1024);
      gl_lds16(Bt + (size_t)(n0 + row) * K + k0 + gch * 8, (char*)Bs + (w * 4 + g) * 1024);
    }
    __syncthreads();
#pragma unroll
    for (int kk = 0; kk < 2; kk++) {
      short8 af[4], bfr[4];
#pragma unroll
      for (int i = 0; i < 4; i++) {
        int row = wr * 64 + i * 16 + r16;
        int pc = (kk * 4 + q4) ^ (r16 & 7);
        af[i] = *(const short8*)((const char*)As + row * 128 + pc * 16);
      }
#pragma unroll
      for (int j = 0; j < 4; j++) {
        int row = wc * 64 + j * 16 + r16;
        int pc = (kk * 4 + q4) ^ (r16 & 7);
        bfr[j] = *(const short8*)((const char*)Bs + row * 128 + pc * 16);
      }
#pragma unroll
      for (int i = 0; i < 4; i++)
#pragma unroll
        for (int j = 0; j < 4; j++) acc[i][j] = mfma16(af[i], bfr[j], acc[i][j]);
    }
    __syncthreads();
  }

  const int nb = n0 + wc * 64 + r16;
  float bn[4];
#pragma unroll
  for (int j = 0; j < 4; j++) bn[j] = bias[nb + j * 16];
#pragma unroll
  for (int i = 0; i < 4; i++) {
#pragma unroll
    for (int r = 0; r < 4; r++) {
      int m = m0 + wr * 64 + i * 16 + q4 * 4 + r;
      if (EPI == 1) {
        float* cp = Cf + (size_t)m * N + nb;
#pragma unroll
        for (int j = 0; j < 4; j++) cp[j * 16] = acc[i][j][r] + bn[j];
      } else {
        u16* cp = Cb + (size_t)m * N + nb;
#pragma unroll
        for (int j = 0; j < 4; j++) cp[j * 16] = f2bf(acc[i][j][r] + bn[j]);
      }
    }
  }
}

// ---------------- attention: one block per (b,h) --------------------------
// Swapped QK^T -> P lane-local -> PV via 16x16x16 MFMA. No-max softmax;
// 1/sum deferred with row-transposing shuffle. THIS ROUND: f16 bias table,
// all 13 loads hoisted as u16x4 before the QK loop (26 VGPR vs 52 fp32) ->
// target VGPR <=128 (3->4 waves/SIMD cliff) + batched L2 latency.
__global__ __launch_bounds__(256) void attn_k(
    const u16* __restrict__ qkv, const u16* __restrict__ be,
    u16* __restrict__ ao) {
  constexpr int VST = 236;
  __shared__ u16 Ks[208 * 32];
  __shared__ u16 Vt[32 * VST];
  const int tid = threadIdx.x, lane = tid & 63, w = tid >> 6;
  const int r16 = lane & 15, q4 = lane >> 4;
  const int bh = blockIdx.x, b = bh / 24, h = bh % 24;
  const u16* qp = qkv + (size_t)(b * 196) * 2304 + h * 32;
  const u16* kp = qp + 768;
  const u16* vp = qp + 1536;
  const u16* bp = be + h * (196 * 208);
  const int ksw = (q4 ^ ((r16 >> 1) & 3)) * 16;
  const float SC2 = 0.17677669529663687f * 1.4426950408889634f;

  for (int g = w; g < 13; g += 4) {
    int chunk = g * 64 + lane;
    int row = chunk >> 2;
    int gch = (chunk & 3) ^ ((row >> 1) & 3);
    gl_lds16(kp + (size_t)row * 2304 + gch * 8, (char*)Ks + g * 1024);
  }
  for (int c = tid; c < 784; c += 256) {
    int n = c >> 2, d0 = (c & 3) * 8;
    u16x8 vv = *(const u16x8*)(vp + (size_t)n * 2304 + (c & 3) * 8);
#pragma unroll
    for (int jj = 0; jj < 8; jj++) Vt[(d0 + jj) * VST + n] = vv[jj];
  }
  for (int idx = tid; idx < 32 * 40; idx += 256) {
    int d = idx / 40, n = 196 + idx % 40;
    Vt[d * VST + n] = 0;
  }
  __syncthreads();

  const f32x4 z = {0.f, 0.f, 0.f, 0.f};
  short8 bq = *(const short8*)(qp + (size_t)(w * 16 + r16) * 2304 + q4 * 8);
  for (int si = w; si < 13; si += 4) {
    short8 bq_next = {};
    if (si + 4 < 13)
      bq_next = *(const short8*)(qp + (size_t)((si + 4) * 16 + r16) * 2304 + q4 * 8);
    int gc = si * 16 + r16;
    gc = gc < 196 ? gc : 195;
    const u16* browh = bp + gc * 208 + q4 * 4;
    // hoisted bias loads: issued as a batch, land under the 13 QK MFMAs
    u16x4 bvh[13];
#pragma unroll
    for (int t = 0; t < 13; t++) bvh[t] = *(const u16x4*)(browh + t * 16);
    float s0 = 0.f, s1 = 0.f, s2 = 0.f, s3 = 0.f;
    short4v pa[13];
#pragma unroll
    for (int t = 0; t < 13; t++) {
      short8 ka = *(const short8*)((const char*)Ks + (t * 16 + r16) * 64 + ksw);
      f32x4 p = mfma16(ka, bq, z);
      float e0 = __builtin_amdgcn_exp2f(p[0] * SC2 + h2f(bvh[t][0]));
      float e1 = __builtin_amdgcn_exp2f(p[1] * SC2 + h2f(bvh[t][1]));
      float e2 = __builtin_amdgcn_exp2f(p[2] * SC2 + h2f(bvh[t][2]));
      float e3 = __builtin_amdgcn_exp2f(p[3] * SC2 + h2f(bvh[t][3]));
      if (t == 12) {  // keys 192..207: mask k >= 196 (kills OOB-K garbage)
        int k0 = 192 + q4 * 4;
        e0 = (k0 + 0 < 196) ? e0 : 0.f;
        e1 = (k0 + 1 < 196) ? e1 : 0.f;
        e2 = (k0 + 2 < 196) ? e2 : 0.f;
        e3 = (k0 + 3 < 196) ? e3 : 0.f;
      }
      s0 += e0; s1 += e1; s2 += e2; s3 += e3;
      pa[t][0] = (short)f2bf(e0);
      pa[t][1] = (short)f2bf(e1);
      pa[t][2] = (short)f2bf(e2);
      pa[t][3] = (short)f2bf(e3);
    }
    bq = bq_next;
    float sum = (s0 + s1) + (s2 + s3);
    sum += __shfl_xor(sum, 16, 64);
    sum += __shfl_xor(sum, 32, 64);
    float rs = 1.0f / sum;
    f32x4 o0a = z, o0b = z, o1a = z, o1b = z;
    __builtin_amdgcn_s_setprio(1);
#pragma unroll
    for (int t = 0; t < 13; t++) {
      const u16* vrow = &Vt[r16 * VST + t * 16 + q4 * 4];
      short4v b0 = *(const short4v*)vrow;
      short4v b1 = *(const short4v*)(vrow + 16 * VST);
      if (t & 1) {
        o0b = mfma16x16(pa[t], b0, o0b);
        o1b = mfma16x16(pa[t], b1, o1b);
      } else {
        o0a = mfma16x16(pa[t], b0, o0a);
        o1a = mfma16x16(pa[t], b1, o1a);
      }
    }
    __builtin_amdgcn_s_setprio(0);
#pragma unroll
    for (int r = 0; r < 4; r++) {
      float rsv = __shfl(rs, q4 * 4 + r, 16);
      int grow = si * 16 + q4 * 4 + r;
      if (grow < 196) {
        u16* op = ao + ((size_t)(b * 196 + grow)) * 768 + h * 32;
        op[r16] = f2bf((o0a[r] + o0b[r]) * rsv);
        op[16 + r16] = f2bf((o1a[r] + o1b[r]) * rsv);
      }
    }
  }
}

// ---------------------------------------------------------------------------
extern "C" void kernel_launch(void* const* d_in, const int* in_sizes, int n_in,
                              void* d_out, int out_size, void* d_ws, size_t ws_size,
                              hipStream_t stream) {
  const float* x = (const float*)d_in[0];
  const float* qkv_w = (const float*)d_in[1];
  const float* qkv_b = (const float*)d_in[2];
  const float* proj_w = (const float*)d_in[3];
  const float* proj_b = (const float*)d_in[4];
  const float* cpb_w1 = (const float*)d_in[5];
  const float* cpb_b1 = (const float*)d_in[6];
  const float* cpb_w2 = (const float*)d_in[7];
  const float* cpb_b2 = (const float*)d_in[8];
  float* out = (float*)d_out;

  char* ws = (char*)d_ws;
  size_t o = 0;
  auto alloc = [&](size_t sz) {
    size_t r = o;
    o = (o + sz + 255) & ~(size_t)255;
    return r;
  };
  const size_t ME = (size_t)25088 * 768;
  u16* x_bf = (u16*)(ws + alloc(ME * 2));           // also aliased as attnout
  u16* wq_t = (u16*)(ws + alloc((size_t)2304 * 768 * 2));
  u16* wp_t = (u16*)(ws + alloc((size_t)768 * 768 * 2));
  u16* qkv_s = (u16*)(ws + alloc(3 * ME * 2));      // [25088][2304] bf16
  float* btab = (float*)(ws + alloc((size_t)729 * 24 * 4));
  u16* bexp = (u16*)(ws + alloc((size_t)24 * 196 * 208 * 2));  // f16 bits
  u16* ao = x_bf;

  cvt_x_k<<<18816, 256, 0, stream>>>(x, x_bf);
  cvt_wt_k<<<dim3(36, 12), 256, 0, stream>>>(qkv_w, wq_t, 2304);
  cvt_wt_k<<<dim3(12, 12), 256, 0, stream>>>(proj_w, wp_t, 768);
  bias_mlp_k<<<729, 64, 0, stream>>>(cpb_w1, cpb_b1, cpb_w2, cpb_b2, btab);
  bias_expand_k<<<3822, 256, 0, stream>>>(btab, bexp);
  gemm_k<0><<<3528, 256, 0, stream>>>(x_bf, wq_t, qkv_b, nullptr, qkv_s,
                                      2304, 768, 18);
  attn_k<<<3072, 256, 0, stream>>>(qkv_s, bexp, ao);
  gemm_k<1><<<1176, 256, 0, stream>>>(ao, wp_t, proj_b, out, nullptr,
                                      768, 768, 6);
}

// Round 14
// 265.576 us; speedup vs baseline: 1.0872x; 1.0162x over previous
//
#include <hip/hip_runtime.h>
#include <hip/hip_bf16.h>

typedef unsigned short u16;
typedef __attribute__((ext_vector_type(8))) short short8;
typedef __attribute__((ext_vector_type(4))) short short4v;
typedef __attribute__((ext_vector_type(8))) u16 u16x8;
typedef __attribute__((ext_vector_type(4))) u16 u16x4;
typedef __attribute__((ext_vector_type(4))) float f32x4;

__device__ __forceinline__ u16 f2bf(float f) {
  __hip_bfloat16 h = __float2bfloat16(f);
  u16 u;
  __builtin_memcpy(&u, &h, 2);
  return u;
}

__device__ __forceinline__ float h2f(u16 h) {
  return (float)__builtin_bit_cast(_Float16, h);
}

__device__ __forceinline__ f32x4 mfma16(short8 a, short8 b, f32x4 c) {
  return __builtin_amdgcn_mfma_f32_16x16x32_bf16(a, b, c, 0, 0, 0);
}

__device__ __forceinline__ f32x4 mfma16x16(short4v a, short4v b, f32x4 c) {
#if __has_builtin(__builtin_amdgcn_mfma_f32_16x16x16bf16_1k)
  return __builtin_amdgcn_mfma_f32_16x16x16bf16_1k(a, b, c, 0, 0, 0);
#else
  asm("v_mfma_f32_16x16x16_bf16 %0, %1, %2, %0" : "+v"(c) : "v"(a), "v"(b));
  return c;
#endif
}

__device__ __forceinline__ void gl_lds16(const void* g, void* l) {
  __builtin_amdgcn_global_load_lds(
      (const __attribute__((address_space(1))) unsigned int*)g,
      (__attribute__((address_space(3))) unsigned int*)l, 16, 0, 0);
}

// ---------------- convert x fp32 -> bf16 ----------------
__global__ __launch_bounds__(256) void cvt_x_k(const float* __restrict__ x,
                                               u16* __restrict__ xb) {
  int i = (blockIdx.x * 256 + threadIdx.x) * 4;
  float4 v = *(const float4*)(x + i);
  u16x4 o = { f2bf(v.x), f2bf(v.y), f2bf(v.z), f2bf(v.w) };
  *(u16x4*)(xb + i) = o;
}

// ------- transpose + convert weight via LDS tile: wt[n][k] = w[k][n] -------
__global__ __launch_bounds__(256) void cvt_wt_k(const float* __restrict__ w,
                                                u16* __restrict__ wt, int N) {
  __shared__ u16 t64[64][65];
  const int n0 = blockIdx.x * 64, k0 = blockIdx.y * 64;
  const int c = threadIdx.x & 63, rg = threadIdx.x >> 6;
#pragma unroll
  for (int r = 0; r < 16; r++) {
    int kk = rg * 16 + r;
    t64[c][kk] = f2bf(w[(size_t)(k0 + kk) * N + n0 + c]);
  }
  __syncthreads();
#pragma unroll
  for (int r = 0; r < 16; r++) {
    int nn = rg * 16 + r;
    wt[(size_t)(n0 + nn) * 768 + k0 + c] = t64[nn][c];
  }
}

// ---------------- CPB bias MLP: 729 entries x (2->512->24), 16*sigmoid -----
__device__ __forceinline__ float cpb_coord(int v) {
  float c = (float)(v - 13) * (8.0f / 13.0f);
  float a = fabsf(c);
  float r = log2f(a + 1.0f) * (1.0f / 3.0f);
  return c < 0.f ? -r : r;
}

__global__ __launch_bounds__(64) void bias_mlp_k(
    const float* __restrict__ w1, const float* __restrict__ b1,
    const float* __restrict__ w2, const float* __restrict__ b2,
    float* __restrict__ btab) {
  int e = blockIdx.x;
  int lane = threadIdx.x;
  float t0 = cpb_coord(e / 27), t1 = cpb_coord(e % 27);
  float acc[24];
#pragma unroll
  for (int hh = 0; hh < 24; hh++) acc[hh] = 0.f;
#pragma unroll
  for (int jj = 0; jj < 8; jj++) {
    int j = lane * 8 + jj;
    float h1 = t0 * w1[j] + t1 * w1[512 + j] + b1[j];
    h1 = fmaxf(h1, 0.f);
#pragma unroll
    for (int hh = 0; hh < 24; hh++) acc[hh] += h1 * w2[j * 24 + hh];
  }
#pragma unroll
  for (int hh = 0; hh < 24; hh++)
#pragma unroll
    for (int m = 1; m < 64; m <<= 1) acc[hh] += __shfl_xor(acc[hh], m, 64);
  if (lane == 0) {
#pragma unroll
    for (int hh = 0; hh < 24; hh++) {
      float v = acc[hh] + b2[hh];
      btab[e * 24 + hh] = 16.f / (1.f + __expf(-v));
    }
  }
}

// --------- expand bias to [24][196][208] f16 bits, pre-scaled by log2e -----
__global__ __launch_bounds__(256) void bias_expand_k(const float* __restrict__ tab,
                                                     u16* __restrict__ be) {
  int i = blockIdx.x * 256 + threadIdx.x;  // 24*196*208
  int h = i / (196 * 208);
  int rem = i % (196 * 208);
  int row = rem / 208, col = rem % 208;
  float v = 0.f;
  if (col < 196) {
    int dy = row / 14 - col / 14 + 13;
    int dx = row % 14 - col % 14 + 13;
    v = tab[(dy * 27 + dx) * 24 + h] * 1.4426950408889634f;
  }
  _Float16 hv = (_Float16)v;
  be[i] = __builtin_bit_cast(unsigned short, hv);
}

// ---------------- GEMM: C = A[M][K] * Bt[N][K]^T + bias -------------------
// 128^2 m97-structure. THIS ROUND: L2 super-tile mapping — within the
// XCD-bijective order, blocks walk groups of (4 m-rows x all n) so the L2
// working set = 4 A-panels (784KB) + full B panel (<=3.4MB) ~ 4MB: B stays
// resident, A fetched once. Requires (#m-blocks % 4 == 0): 196 % 4 == 0 ok.
// EPI=0: bf16 out; EPI=1: fp32 out.
template <int EPI>
__global__ __launch_bounds__(256) void gemm_k(
    const u16* __restrict__ A, const u16* __restrict__ Bt,
    const float* __restrict__ bias, float* __restrict__ Cf,
    u16* __restrict__ Cb, int N, int K, int nbx) {
  __shared__ u16 As[128 * 64];
  __shared__ u16 Bs[128 * 64];
  const int tid = threadIdx.x, lane = tid & 63, w = tid >> 6;
  const int r16 = lane & 15, q4 = lane >> 4;
  const int wr = w >> 1, wc = w & 1;
  const int nwg = gridDim.x, cpx = nwg >> 3;
  const int swz = (blockIdx.x & 7) * cpx + (blockIdx.x >> 3);
  // super-tile decode: group of 4 m-rows x nbx n-cols
  const int gsz = nbx * 4;
  const int mgrp = swz / gsz, rem = swz % gsz;
  const int m0 = (mgrp * 4 + rem / nbx) * 128, n0 = (rem % nbx) * 128;

  f32x4 acc[4][4] = {};

  for (int k0 = 0; k0 < K; k0 += 64) {
#pragma unroll
    for (int g = 0; g < 4; g++) {
      int chunk = (w * 4 + g) * 64 + lane;
      int row = chunk >> 3, p = chunk & 7;
      int gch = p ^ (row & 7);
      gl_lds16(A + (size_t)(m0 + row) * K + k0 + gch * 8, (char*)As + (w * 4 + g) * 1024);
      gl_lds16(Bt + (size_t)(n0 + row) * K + k0 + gch * 8, (char*)Bs + (w * 4 + g) * 1024);
    }
    __syncthreads();
#pragma unroll
    for (int kk = 0; kk < 2; kk++) {
      short8 af[4], bfr[4];
#pragma unroll
      for (int i = 0; i < 4; i++) {
        int row = wr * 64 + i * 16 + r16;
        int pc = (kk * 4 + q4) ^ (r16 & 7);
        af[i] = *(const short8*)((const char*)As + row * 128 + pc * 16);
      }
#pragma unroll
      for (int j = 0; j < 4; j++) {
        int row = wc * 64 + j * 16 + r16;
        int pc = (kk * 4 + q4) ^ (r16 & 7);
        bfr[j] = *(const short8*)((const char*)Bs + row * 128 + pc * 16);
      }
#pragma unroll
      for (int i = 0; i < 4; i++)
#pragma unroll
        for (int j = 0; j < 4; j++) acc[i][j] = mfma16(af[i], bfr[j], acc[i][j]);
    }
    __syncthreads();
  }

  const int nb = n0 + wc * 64 + r16;
  float bn[4];
#pragma unroll
  for (int j = 0; j < 4; j++) bn[j] = bias[nb + j * 16];
#pragma unroll
  for (int i = 0; i < 4; i++) {
#pragma unroll
    for (int r = 0; r < 4; r++) {
      int m = m0 + wr * 64 + i * 16 + q4 * 4 + r;
      if (EPI == 1) {
        float* cp = Cf + (size_t)m * N + nb;
#pragma unroll
        for (int j = 0; j < 4; j++) cp[j * 16] = acc[i][j][r] + bn[j];
      } else {
        u16* cp = Cb + (size_t)m * N + nb;
#pragma unroll
        for (int j = 0; j < 4; j++) cp[j * 16] = f2bf(acc[i][j][r] + bn[j]);
      }
    }
  }
}

// ---------------- attention: one block per (b,h) --------------------------
// Swapped QK^T -> P lane-local -> PV via 16x16x16 MFMA. No-max softmax;
// 1/sum deferred with row-transposing shuffle. f16 bias table, loads hoisted.
// (Unchanged control this round.)
__global__ __launch_bounds__(256) void attn_k(
    const u16* __restrict__ qkv, const u16* __restrict__ be,
    u16* __restrict__ ao) {
  constexpr int VST = 236;
  __shared__ u16 Ks[208 * 32];
  __shared__ u16 Vt[32 * VST];
  const int tid = threadIdx.x, lane = tid & 63, w = tid >> 6;
  const int r16 = lane & 15, q4 = lane >> 4;
  const int bh = blockIdx.x, b = bh / 24, h = bh % 24;
  const u16* qp = qkv + (size_t)(b * 196) * 2304 + h * 32;
  const u16* kp = qp + 768;
  const u16* vp = qp + 1536;
  const u16* bp = be + h * (196 * 208);
  const int ksw = (q4 ^ ((r16 >> 1) & 3)) * 16;
  const float SC2 = 0.17677669529663687f * 1.4426950408889634f;

  for (int g = w; g < 13; g += 4) {
    int chunk = g * 64 + lane;
    int row = chunk >> 2;
    int gch = (chunk & 3) ^ ((row >> 1) & 3);
    gl_lds16(kp + (size_t)row * 2304 + gch * 8, (char*)Ks + g * 1024);
  }
  for (int c = tid; c < 784; c += 256) {
    int n = c >> 2, d0 = (c & 3) * 8;
    u16x8 vv = *(const u16x8*)(vp + (size_t)n * 2304 + (c & 3) * 8);
#pragma unroll
    for (int jj = 0; jj < 8; jj++) Vt[(d0 + jj) * VST + n] = vv[jj];
  }
  for (int idx = tid; idx < 32 * 40; idx += 256) {
    int d = idx / 40, n = 196 + idx % 40;
    Vt[d * VST + n] = 0;
  }
  __syncthreads();

  const f32x4 z = {0.f, 0.f, 0.f, 0.f};
  short8 bq = *(const short8*)(qp + (size_t)(w * 16 + r16) * 2304 + q4 * 8);
  for (int si = w; si < 13; si += 4) {
    short8 bq_next = {};
    if (si + 4 < 13)
      bq_next = *(const short8*)(qp + (size_t)((si + 4) * 16 + r16) * 2304 + q4 * 8);
    int gc = si * 16 + r16;
    gc = gc < 196 ? gc : 195;
    const u16* browh = bp + gc * 208 + q4 * 4;
    u16x4 bvh[13];
#pragma unroll
    for (int t = 0; t < 13; t++) bvh[t] = *(const u16x4*)(browh + t * 16);
    float s0 = 0.f, s1 = 0.f, s2 = 0.f, s3 = 0.f;
    short4v pa[13];
#pragma unroll
    for (int t = 0; t < 13; t++) {
      short8 ka = *(const short8*)((const char*)Ks + (t * 16 + r16) * 64 + ksw);
      f32x4 p = mfma16(ka, bq, z);
      float e0 = __builtin_amdgcn_exp2f(p[0] * SC2 + h2f(bvh[t][0]));
      float e1 = __builtin_amdgcn_exp2f(p[1] * SC2 + h2f(bvh[t][1]));
      float e2 = __builtin_amdgcn_exp2f(p[2] * SC2 + h2f(bvh[t][2]));
      float e3 = __builtin_amdgcn_exp2f(p[3] * SC2 + h2f(bvh[t][3]));
      if (t == 12) {
        int k0 = 192 + q4 * 4;
        e0 = (k0 + 0 < 196) ? e0 : 0.f;
        e1 = (k0 + 1 < 196) ? e1 : 0.f;
        e2 = (k0 + 2 < 196) ? e2 : 0.f;
        e3 = (k0 + 3 < 196) ? e3 : 0.f;
      }
      s0 += e0; s1 += e1; s2 += e2; s3 += e3;
      pa[t][0] = (short)f2bf(e0);
      pa[t][1] = (short)f2bf(e1);
      pa[t][2] = (short)f2bf(e2);
      pa[t][3] = (short)f2bf(e3);
    }
    bq = bq_next;
    float sum = (s0 + s1) + (s2 + s3);
    sum += __shfl_xor(sum, 16, 64);
    sum += __shfl_xor(sum, 32, 64);
    float rs = 1.0f / sum;
    f32x4 o0a = z, o0b = z, o1a = z, o1b = z;
    __builtin_amdgcn_s_setprio(1);
#pragma unroll
    for (int t = 0; t < 13; t++) {
      const u16* vrow = &Vt[r16 * VST + t * 16 + q4 * 4];
      short4v b0 = *(const short4v*)vrow;
      short4v b1 = *(const short4v*)(vrow + 16 * VST);
      if (t & 1) {
        o0b = mfma16x16(pa[t], b0, o0b);
        o1b = mfma16x16(pa[t], b1, o1b);
      } else {
        o0a = mfma16x16(pa[t], b0, o0a);
        o1a = mfma16x16(pa[t], b1, o1a);
      }
    }
    __builtin_amdgcn_s_setprio(0);
#pragma unroll
    for (int r = 0; r < 4; r++) {
      float rsv = __shfl(rs, q4 * 4 + r, 16);
      int grow = si * 16 + q4 * 4 + r;
      if (grow < 196) {
        u16* op = ao + ((size_t)(b * 196 + grow)) * 768 + h * 32;
        op[r16] = f2bf((o0a[r] + o0b[r]) * rsv);
        op[16 + r16] = f2bf((o1a[r] + o1b[r]) * rsv);
      }
    }
  }
}

// ---------------------------------------------------------------------------
extern "C" void kernel_launch(void* const* d_in, const int* in_sizes, int n_in,
                              void* d_out, int out_size, void* d_ws, size_t ws_size,
                              hipStream_t stream) {
  const float* x = (const float*)d_in[0];
  const float* qkv_w = (const float*)d_in[1];
  const float* qkv_b = (const float*)d_in[2];
  const float* proj_w = (const float*)d_in[3];
  const float* proj_b = (const float*)d_in[4];
  const float* cpb_w1 = (const float*)d_in[5];
  const float* cpb_b1 = (const float*)d_in[6];
  const float* cpb_w2 = (const float*)d_in[7];
  const float* cpb_b2 = (const float*)d_in[8];
  float* out = (float*)d_out;

  char* ws = (char*)d_ws;
  size_t o = 0;
  auto alloc = [&](size_t sz) {
    size_t r = o;
    o = (o + sz + 255) & ~(size_t)255;
    return r;
  };
  const size_t ME = (size_t)25088 * 768;
  u16* x_bf = (u16*)(ws + alloc(ME * 2));           // also aliased as attnout
  u16* wq_t = (u16*)(ws + alloc((size_t)2304 * 768 * 2));
  u16* wp_t = (u16*)(ws + alloc((size_t)768 * 768 * 2));
  u16* qkv_s = (u16*)(ws + alloc(3 * ME * 2));      // [25088][2304] bf16
  float* btab = (float*)(ws + alloc((size_t)729 * 24 * 4));
  u16* bexp = (u16*)(ws + alloc((size_t)24 * 196 * 208 * 2));  // f16 bits
  u16* ao = x_bf;

  cvt_x_k<<<18816, 256, 0, stream>>>(x, x_bf);
  cvt_wt_k<<<dim3(36, 12), 256, 0, stream>>>(qkv_w, wq_t, 2304);
  cvt_wt_k<<<dim3(12, 12), 256, 0, stream>>>(proj_w, wp_t, 768);
  bias_mlp_k<<<729, 64, 0, stream>>>(cpb_w1, cpb_b1, cpb_w2, cpb_b2, btab);
  bias_expand_k<<<3822, 256, 0, stream>>>(btab, bexp);
  gemm_k<0><<<3528, 256, 0, stream>>>(x_bf, wq_t, qkv_b, nullptr, qkv_s,
                                      2304, 768, 18);
  attn_k<<<3072, 256, 0, stream>>>(qkv_s, bexp, ao);
  gemm_k<1><<<1176, 256, 0, stream>>>(ao, wp_t, proj_b, out, nullptr,
                                      768, 768, 6);
}

// Round 15
// 263.752 us; speedup vs baseline: 1.0947x; 1.0069x over previous
//
#include <hip/hip_runtime.h>
#include <hip/hip_bf16.h>

typedef unsigned short u16;
typedef __attribute__((ext_vector_type(8))) short short8;
typedef __attribute__((ext_vector_type(4))) short short4v;
typedef __attribute__((ext_vector_type(8))) u16 u16x8;
typedef __attribute__((ext_vector_type(4))) u16 u16x4;
typedef __attribute__((ext_vector_type(4))) float f32x4;

__device__ __forceinline__ u16 f2bf(float f) {
  __hip_bfloat16 h = __float2bfloat16(f);
  u16 u;
  __builtin_memcpy(&u, &h, 2);
  return u;
}

__device__ __forceinline__ float h2f(u16 h) {
  return (float)__builtin_bit_cast(_Float16, h);
}

__device__ __forceinline__ f32x4 mfma16(short8 a, short8 b, f32x4 c) {
  return __builtin_amdgcn_mfma_f32_16x16x32_bf16(a, b, c, 0, 0, 0);
}

__device__ __forceinline__ f32x4 mfma16x16(short4v a, short4v b, f32x4 c) {
#if __has_builtin(__builtin_amdgcn_mfma_f32_16x16x16bf16_1k)
  return __builtin_amdgcn_mfma_f32_16x16x16bf16_1k(a, b, c, 0, 0, 0);
#else
  asm("v_mfma_f32_16x16x16_bf16 %0, %1, %2, %0" : "+v"(c) : "v"(a), "v"(b));
  return c;
#endif
}

__device__ __forceinline__ void gl_lds16(const void* g, void* l) {
  __builtin_amdgcn_global_load_lds(
      (const __attribute__((address_space(1))) unsigned int*)g,
      (__attribute__((address_space(3))) unsigned int*)l, 16, 0, 0);
}

// ---------------- convert x fp32 -> bf16 ----------------
__global__ __launch_bounds__(256) void cvt_x_k(const float* __restrict__ x,
                                               u16* __restrict__ xb) {
  int i = (blockIdx.x * 256 + threadIdx.x) * 4;
  float4 v = *(const float4*)(x + i);
  u16x4 o = { f2bf(v.x), f2bf(v.y), f2bf(v.z), f2bf(v.w) };
  *(u16x4*)(xb + i) = o;
}

// ------- transpose + convert weight via LDS tile: wt[n][k] = w[k][n] -------
__global__ __launch_bounds__(256) void cvt_wt_k(const float* __restrict__ w,
                                                u16* __restrict__ wt, int N) {
  __shared__ u16 t64[64][65];
  const int n0 = blockIdx.x * 64, k0 = blockIdx.y * 64;
  const int c = threadIdx.x & 63, rg = threadIdx.x >> 6;
#pragma unroll
  for (int r = 0; r < 16; r++) {
    int kk = rg * 16 + r;
    t64[c][kk] = f2bf(w[(size_t)(k0 + kk) * N + n0 + c]);
  }
  __syncthreads();
#pragma unroll
  for (int r = 0; r < 16; r++) {
    int nn = rg * 16 + r;
    wt[(size_t)(n0 + nn) * 768 + k0 + c] = t64[nn][c];
  }
}

// ---------------- CPB bias MLP: 729 entries x (2->512->24), 16*sigmoid -----
__device__ __forceinline__ float cpb_coord(int v) {
  float c = (float)(v - 13) * (8.0f / 13.0f);
  float a = fabsf(c);
  float r = log2f(a + 1.0f) * (1.0f / 3.0f);
  return c < 0.f ? -r : r;
}

__global__ __launch_bounds__(64) void bias_mlp_k(
    const float* __restrict__ w1, const float* __restrict__ b1,
    const float* __restrict__ w2, const float* __restrict__ b2,
    float* __restrict__ btab) {
  int e = blockIdx.x;
  int lane = threadIdx.x;
  float t0 = cpb_coord(e / 27), t1 = cpb_coord(e % 27);
  float acc[24];
#pragma unroll
  for (int hh = 0; hh < 24; hh++) acc[hh] = 0.f;
#pragma unroll
  for (int jj = 0; jj < 8; jj++) {
    int j = lane * 8 + jj;
    float h1 = t0 * w1[j] + t1 * w1[512 + j] + b1[j];
    h1 = fmaxf(h1, 0.f);
#pragma unroll
    for (int hh = 0; hh < 24; hh++) acc[hh] += h1 * w2[j * 24 + hh];
  }
#pragma unroll
  for (int hh = 0; hh < 24; hh++)
#pragma unroll
    for (int m = 1; m < 64; m <<= 1) acc[hh] += __shfl_xor(acc[hh], m, 64);
  if (lane == 0) {
#pragma unroll
    for (int hh = 0; hh < 24; hh++) {
      float v = acc[hh] + b2[hh];
      btab[e * 24 + hh] = 16.f / (1.f + __expf(-v));
    }
  }
}

// --------- expand bias to [24][196][208] f16 bits, pre-scaled by log2e -----
__global__ __launch_bounds__(256) void bias_expand_k(const float* __restrict__ tab,
                                                     u16* __restrict__ be) {
  int i = blockIdx.x * 256 + threadIdx.x;  // 24*196*208
  int h = i / (196 * 208);
  int rem = i % (196 * 208);
  int row = rem / 208, col = rem % 208;
  float v = 0.f;
  if (col < 196) {
    int dy = row / 14 - col / 14 + 13;
    int dx = row % 14 - col % 14 + 13;
    v = tab[(dy * 27 + dx) * 24 + h] * 1.4426950408889634f;
  }
  _Float16 hv = (_Float16)v;
  be[i] = __builtin_bit_cast(unsigned short, hv);
}

// ---------------- GEMM: C = A[M][K] * Bt[N][K]^T + bias -------------------
// 128^2 m97-structure. THIS ROUND: L2 super-tile mapping — within the
// XCD-bijective order, blocks walk groups of (4 m-rows x all n) so the L2
// working set = 4 A-panels (784KB) + full B panel (<=3.4MB) ~ 4MB: B stays
// resident, A fetched once. Requires (#m-blocks % 4 == 0): 196 % 4 == 0 ok.
// EPI=0: bf16 out; EPI=1: fp32 out.
template <int EPI>
__global__ __launch_bounds__(256) void gemm_k(
    const u16* __restrict__ A, const u16* __restrict__ Bt,
    const float* __restrict__ bias, float* __restrict__ Cf,
    u16* __restrict__ Cb, int N, int K, int nbx) {
  __shared__ u16 As[128 * 64];
  __shared__ u16 Bs[128 * 64];
  const int tid = threadIdx.x, lane = tid & 63, w = tid >> 6;
  const int r16 = lane & 15, q4 = lane >> 4;
  const int wr = w >> 1, wc = w & 1;
  const int nwg = gridDim.x, cpx = nwg >> 3;
  const int swz = (blockIdx.x & 7) * cpx + (blockIdx.x >> 3);
  // super-tile decode: group of 4 m-rows x nbx n-cols
  const int gsz = nbx * 4;
  const int mgrp = swz / gsz, rem = swz % gsz;
  const int m0 = (mgrp * 4 + rem / nbx) * 128, n0 = (rem % nbx) * 128;

  f32x4 acc[4][4] = {};

  for (int k0 = 0; k0 < K; k0 += 64) {
#pragma unroll
    for (int g = 0; g < 4; g++) {
      int chunk = (w * 4 + g) * 64 + lane;
      int row = chunk >> 3, p = chunk & 7;
      int gch = p ^ (row & 7);
      gl_lds16(A + (size_t)(m0 + row) * K + k0 + gch * 8, (char*)As + (w * 4 + g) * 1024);
      gl_lds16(Bt + (size_t)(n0 + row) * K + k0 + gch * 8, (char*)Bs + (w * 4 + g) * 1024);
    }
    __syncthreads();
#pragma unroll
    for (int kk = 0; kk < 2; kk++) {
      short8 af[4], bfr[4];
#pragma unroll
      for (int i = 0; i < 4; i++) {
        int row = wr * 64 + i * 16 + r16;
        int pc = (kk * 4 + q4) ^ (r16 & 7);
        af[i] = *(const short8*)((const char*)As + row * 128 + pc * 16);
      }
#pragma unroll
      for (int j = 0; j < 4; j++) {
        int row = wc * 64 + j * 16 + r16;
        int pc = (kk * 4 + q4) ^ (r16 & 7);
        bfr[j] = *(const short8*)((const char*)Bs + row * 128 + pc * 16);
      }
#pragma unroll
      for (int i = 0; i < 4; i++)
#pragma unroll
        for (int j = 0; j < 4; j++) acc[i][j] = mfma16(af[i], bfr[j], acc[i][j]);
    }
    __syncthreads();
  }

  const int nb = n0 + wc * 64 + r16;
  float bn[4];
#pragma unroll
  for (int j = 0; j < 4; j++) bn[j] = bias[nb + j * 16];
#pragma unroll
  for (int i = 0; i < 4; i++) {
#pragma unroll
    for (int r = 0; r < 4; r++) {
      int m = m0 + wr * 64 + i * 16 + q4 * 4 + r;
      if (EPI == 1) {
        float* cp = Cf + (size_t)m * N + nb;
#pragma unroll
        for (int j = 0; j < 4; j++) cp[j * 16] = acc[i][j][r] + bn[j];
      } else {
        u16* cp = Cb + (size_t)m * N + nb;
#pragma unroll
        for (int j = 0; j < 4; j++) cp[j * 16] = f2bf(acc[i][j][r] + bn[j]);
      }
    }
  }
}

// ---------------- attention: one block per (b,h) --------------------------
// Swapped QK^T -> P lane-local -> PV via 16x16x16 MFMA. No-max softmax;
// 1/sum deferred with row-transposing shuffle. f16 bias table, loads hoisted.
// (Unchanged control this round.)
__global__ __launch_bounds__(256) void attn_k(
    const u16* __restrict__ qkv, const u16* __restrict__ be,
    u16* __restrict__ ao) {
  constexpr int VST = 236;
  __shared__ u16 Ks[208 * 32];
  __shared__ u16 Vt[32 * VST];
  const int tid = threadIdx.x, lane = tid & 63, w = tid >> 6;
  const int r16 = lane & 15, q4 = lane >> 4;
  const int bh = blockIdx.x, b = bh / 24, h = bh % 24;
  const u16* qp = qkv + (size_t)(b * 196) * 2304 + h * 32;
  const u16* kp = qp + 768;
  const u16* vp = qp + 1536;
  const u16* bp = be + h * (196 * 208);
  const int ksw = (q4 ^ ((r16 >> 1) & 3)) * 16;
  const float SC2 = 0.17677669529663687f * 1.4426950408889634f;

  for (int g = w; g < 13; g += 4) {
    int chunk = g * 64 + lane;
    int row = chunk >> 2;
    int gch = (chunk & 3) ^ ((row >> 1) & 3);
    gl_lds16(kp + (size_t)row * 2304 + gch * 8, (char*)Ks + g * 1024);
  }
  for (int c = tid; c < 784; c += 256) {
    int n = c >> 2, d0 = (c & 3) * 8;
    u16x8 vv = *(const u16x8*)(vp + (size_t)n * 2304 + (c & 3) * 8);
#pragma unroll
    for (int jj = 0; jj < 8; jj++) Vt[(d0 + jj) * VST + n] = vv[jj];
  }
  for (int idx = tid; idx < 32 * 40; idx += 256) {
    int d = idx / 40, n = 196 + idx % 40;
    Vt[d * VST + n] = 0;
  }
  __syncthreads();

  const f32x4 z = {0.f, 0.f, 0.f, 0.f};
  short8 bq = *(const short8*)(qp + (size_t)(w * 16 + r16) * 2304 + q4 * 8);
  for (int si = w; si < 13; si += 4) {
    short8 bq_next = {};
    if (si + 4 < 13)
      bq_next = *(const short8*)(qp + (size_t)((si + 4) * 16 + r16) * 2304 + q4 * 8);
    int gc = si * 16 + r16;
    gc = gc < 196 ? gc : 195;
    const u16* browh = bp + gc * 208 + q4 * 4;
    u16x4 bvh[13];
#pragma unroll
    for (int t = 0; t < 13; t++) bvh[t] = *(const u16x4*)(browh + t * 16);
    float s0 = 0.f, s1 = 0.f, s2 = 0.f, s3 = 0.f;
    short4v pa[13];
#pragma unroll
    for (int t = 0; t < 13; t++) {
      short8 ka = *(const short8*)((const char*)Ks + (t * 16 + r16) * 64 + ksw);
      f32x4 p = mfma16(ka, bq, z);
      float e0 = __builtin_amdgcn_exp2f(p[0] * SC2 + h2f(bvh[t][0]));
      float e1 = __builtin_amdgcn_exp2f(p[1] * SC2 + h2f(bvh[t][1]));
      float e2 = __builtin_amdgcn_exp2f(p[2] * SC2 + h2f(bvh[t][2]));
      float e3 = __builtin_amdgcn_exp2f(p[3] * SC2 + h2f(bvh[t][3]));
      if (t == 12) {
        int k0 = 192 + q4 * 4;
        e0 = (k0 + 0 < 196) ? e0 : 0.f;
        e1 = (k0 + 1 < 196) ? e1 : 0.f;
        e2 = (k0 + 2 < 196) ? e2 : 0.f;
        e3 = (k0 + 3 < 196) ? e3 : 0.f;
      }
      s0 += e0; s1 += e1; s2 += e2; s3 += e3;
      pa[t][0] = (short)f2bf(e0);
      pa[t][1] = (short)f2bf(e1);
      pa[t][2] = (short)f2bf(e2);
      pa[t][3] = (short)f2bf(e3);
    }
    bq = bq_next;
    float sum = (s0 + s1) + (s2 + s3);
    sum += __shfl_xor(sum, 16, 64);
    sum += __shfl_xor(sum, 32, 64);
    float rs = 1.0f / sum;
    f32x4 o0a = z, o0b = z, o1a = z, o1b = z;
    __builtin_amdgcn_s_setprio(1);
#pragma unroll
    for (int t = 0; t < 13; t++) {
      const u16* vrow = &Vt[r16 * VST + t * 16 + q4 * 4];
      short4v b0 = *(const short4v*)vrow;
      short4v b1 = *(const short4v*)(vrow + 16 * VST);
      if (t & 1) {
        o0b = mfma16x16(pa[t], b0, o0b);
        o1b = mfma16x16(pa[t], b1, o1b);
      } else {
        o0a = mfma16x16(pa[t], b0, o0a);
        o1a = mfma16x16(pa[t], b1, o1a);
      }
    }
    __builtin_amdgcn_s_setprio(0);
#pragma unroll
    for (int r = 0; r < 4; r++) {
      float rsv = __shfl(rs, q4 * 4 + r, 16);
      int grow = si * 16 + q4 * 4 + r;
      if (grow < 196) {
        u16* op = ao + ((size_t)(b * 196 + grow)) * 768 + h * 32;
        op[r16] = f2bf((o0a[r] + o0b[r]) * rsv);
        op[16 + r16] = f2bf((o1a[r] + o1b[r]) * rsv);
      }
    }
  }
}

// ---------------------------------------------------------------------------
extern "C" void kernel_launch(void* const* d_in, const int* in_sizes, int n_in,
                              void* d_out, int out_size, void* d_ws, size_t ws_size,
                              hipStream_t stream) {
  const float* x = (const float*)d_in[0];
  const float* qkv_w = (const float*)d_in[1];
  const float* qkv_b = (const float*)d_in[2];
  const float* proj_w = (const float*)d_in[3];
  const float* proj_b = (const float*)d_in[4];
  const float* cpb_w1 = (const float*)d_in[5];
  const float* cpb_b1 = (const float*)d_in[6];
  const float* cpb_w2 = (const float*)d_in[7];
  const float* cpb_b2 = (const float*)d_in[8];
  float* out = (float*)d_out;

  char* ws = (char*)d_ws;
  size_t o = 0;
  auto alloc = [&](size_t sz) {
    size_t r = o;
    o = (o + sz + 255) & ~(size_t)255;
    return r;
  };
  const size_t ME = (size_t)25088 * 768;
  u16* x_bf = (u16*)(ws + alloc(ME * 2));           // also aliased as attnout
  u16* wq_t = (u16*)(ws + alloc((size_t)2304 * 768 * 2));
  u16* wp_t = (u16*)(ws + alloc((size_t)768 * 768 * 2));
  u16* qkv_s = (u16*)(ws + alloc(3 * ME * 2));      // [25088][2304] bf16
  float* btab = (float*)(ws + alloc((size_t)729 * 24 * 4));
  u16* bexp = (u16*)(ws + alloc((size_t)24 * 196 * 208 * 2));  // f16 bits
  u16* ao = x_bf;

  cvt_x_k<<<18816, 256, 0, stream>>>(x, x_bf);
  cvt_wt_k<<<dim3(36, 12), 256, 0, stream>>>(qkv_w, wq_t, 2304);
  cvt_wt_k<<<dim3(12, 12), 256, 0, stream>>>(proj_w, wp_t, 768);
  bias_mlp_k<<<729, 64, 0, stream>>>(cpb_w1, cpb_b1, cpb_w2, cpb_b2, btab);
  bias_expand_k<<<3822, 256, 0, stream>>>(btab, bexp);
  gemm_k<0><<<3528, 256, 0, stream>>>(x_bf, wq_t, qkv_b, nullptr, qkv_s,
                                      2304, 768, 18);
  attn_k<<<3072, 256, 0, stream>>>(qkv_s, bexp, ao);
  gemm_k<1><<<1176, 256, 0, stream>>>(ao, wp_t, proj_b, out, nullptr,
                                      768, 768, 6);
}